// Round 16
// baseline (310.837 us; speedup 1.0000x reference)
//
#include <hip/hip_runtime.h>
#include <hip/hip_bf16.h>
#include <math.h>

#define B_    16
#define L_    2048
#define H_    512
#define NT_   8
#define OUT_  1032
#define HEAD_ 256
#define CH_   16
#define CL_   (L_/CH_)   // 128
#define NWS_  1024       // AT row stride in shorts (tight: full-line writes)

// k5 A-LDS geometry: 32 rows, 136 chunks of 16B (2176B row), XOR-swizzled
#define ACH_  136
#define ASTR_ (ACH_*8)   // shorts per row = 1088
#define RB5_  32         // rows per k5 block

typedef short bf16x8 __attribute__((ext_vector_type(8)));
typedef float f32x4  __attribute__((ext_vector_type(4)));

__device__ __forceinline__ float b2f(unsigned short u) {
    union { unsigned int u32; float f; } v; v.u32 = ((unsigned int)u) << 16; return v.f;
}
__device__ __forceinline__ unsigned short f2b(float f) {
    __hip_bfloat16 h = __float2bfloat16(f);
    return *reinterpret_cast<unsigned short*>(&h);
}
__device__ __forceinline__ float sigmoid_f(float x) {
    return 1.f / (1.f + exp2f(-1.44269504f * x));
}
__device__ __forceinline__ float tanh_f(float x) {
    float e = exp2f(2.88539008f * x);
    return 1.f - 2.f / (e + 1.f);
}
__device__ __forceinline__ float gelu_f(float g) {
    float u  = 0.70710678118654752f * g;
    float ax = fabsf(u);
    float t  = 1.f / (1.f + 0.3275911f * ax);
    float poly = ((((1.061405429f*t - 1.453152027f)*t + 1.421413741f)*t
                   - 0.284496736f)*t + 0.254829592f)*t;
    float e  = exp2f(-1.44269504f * ax * ax);
    float er = 1.f - poly * e;
    er = (u < 0.f) ? -er : er;
    return 0.5f * g * (1.f + er);
}

// ---------------------------------------------------------------------------
// kT: transpose + f32->bf16. in f32 [R][C] -> out bf16 [C][RP], zero r>=R.
// ---------------------------------------------------------------------------
__global__ __launch_bounds__(256) void kT(const float* __restrict__ in,
                                          unsigned short* __restrict__ out,
                                          int R, int C, int RP)
{
    __shared__ float tile[32][33];
    int c0 = blockIdx.x * 32, r0 = blockIdx.y * 32;
    int tx = threadIdx.x & 31, ty = threadIdx.x >> 5;
    #pragma unroll
    for (int j = 0; j < 32; j += 8) {
        int r = r0 + ty + j, c = c0 + tx;
        tile[ty + j][tx] = (r < R && c < C) ? in[(size_t)r*C + c] : 0.f;
    }
    __syncthreads();
    #pragma unroll
    for (int j = 0; j < 32; j += 8) {
        int c = c0 + ty + j, r = r0 + tx;
        if (c < C && r < RP) out[(size_t)c*RP + r] = f2b(tile[tx][ty + j]);
    }
}

// ---------------------------------------------------------------------------
// kP: pack Wg1 (f32 [OUT_][256]) into MFMA B-fragment chunks, 33 K-blocks.
// ---------------------------------------------------------------------------
__global__ __launch_bounds__(256) void kP(const float* __restrict__ Wg1,
                                          uint4* __restrict__ P)
{
    int idx = blockIdx.x*256 + threadIdx.x;
    if (idx >= 33*1024) return;
    int kb = idx >> 10;
    int rem = idx & 1023;
    int c  = rem >> 2;
    int kg = rem & 3;
    int k0 = kb*32 + kg*8;
    unsigned short o[8];
    #pragma unroll
    for (int j = 0; j < 8; j++) {
        int k = k0 + j;
        o[j] = (k < OUT_) ? f2b(Wg1[(size_t)k*HEAD_ + c]) : (unsigned short)0;
    }
    P[idx] = *(const uint4*)o;
}

// ---------------------------------------------------------------------------
// K1 (both dirs): t_enc MLP + inp_{f,b} = xc @ Wp{f,b} + bp{f,b}. wave-per-row.
// ---------------------------------------------------------------------------
__global__ __launch_bounds__(256) void k1_tenc_inp(
    const float* __restrict__ x, const float* __restrict__ t,
    const float* __restrict__ Wt1, const float* __restrict__ bt1,
    const float* __restrict__ Wt2, const float* __restrict__ bt2,
    const float* __restrict__ Wpf, const float* __restrict__ bpf,
    const float* __restrict__ Wpb, const float* __restrict__ bpb,
    float* __restrict__ t_enc,
    unsigned short* __restrict__ inp_f, unsigned short* __restrict__ inp_b)
{
    int wv = threadIdx.x >> 6, lane = threadIdx.x & 63;
    size_t row = (size_t)blockIdx.x*4 + wv;
    float tv = t[row];
    float r1[NT_], te[NT_];
    #pragma unroll
    for (int k = 0; k < NT_; k++) r1[k] = fmaxf(tv*Wt1[k] + bt1[k], 0.f);
    #pragma unroll
    for (int j = 0; j < NT_; j++) {
        float a = bt2[j];
        #pragma unroll
        for (int k = 0; k < NT_; k++) a = fmaf(r1[k], Wt2[k*NT_+j], a);
        te[j] = a;
    }
    if (lane < NT_) t_enc[row*NT_ + lane] = te[lane];
    float x0 = x[row*2+0], x1 = x[row*2+1];
    int c0 = lane*8;
    float af[8], ab[8];
    #pragma unroll
    for (int j = 0; j < 8; j++) {
        int c = c0 + j;
        af[j] = fmaf(x0, Wpf[c], fmaf(x1, Wpf[H_+c], bpf[c]));
        ab[j] = fmaf(x0, Wpb[c], fmaf(x1, Wpb[H_+c], bpb[c]));
    }
    #pragma unroll
    for (int k = 0; k < NT_; k++) {
        #pragma unroll
        for (int j = 0; j < 8; j++) {
            af[j] = fmaf(te[k], Wpf[(2+k)*H_+c0+j], af[j]);
            ab[j] = fmaf(te[k], Wpb[(2+k)*H_+c0+j], ab[j]);
        }
    }
    unsigned short of[8], ob[8];
    #pragma unroll
    for (int j = 0; j < 8; j++) { of[j] = f2b(af[j]); ob[j] = f2b(ab[j]); }
    *(uint4*)&inp_f[row*H_ + c0] = *(const uint4*)of;
    *(uint4*)&inp_b[row*H_ + c0] = *(const uint4*)ob;
}

// ---------------------------------------------------------------------------
// K3g (both dirs): AT{F,B}[row][0..1023] = inp{f,b} @ [Wz|Wh].
// 128x128 tile, BK=32. NEW: fragment-order LDS (pre-swizzled global source):
// slot u holds row (u>>6)*16+(u&15), chunk (u>>4)&3. LDS writes lane-linear
// (conflict-free) and frag reads lane-linear (conflict-free). Register
// prefetch of next K-step; XCD remap.
// ---------------------------------------------------------------------------
__global__ __launch_bounds__(256) void k3g(
    const unsigned short* __restrict__ inpF,
    const unsigned short* __restrict__ inpB,
    const unsigned short* __restrict__ WTf,   // [1024][512] (Wz rows, Wh rows)
    const unsigned short* __restrict__ WTb,
    unsigned short* __restrict__ ATF,
    unsigned short* __restrict__ ATB,
    int nwg, int halfTiles)
{
    __shared__ __align__(16) uint4 As2[512];   // 8 KB
    __shared__ __align__(16) uint4 Bs2[512];   // 8 KB
    int tid = threadIdx.x;
    int lane = tid & 63, w = tid >> 6;
    int wm = w >> 1, wn = w & 1;
    int kg = lane >> 4, lr = lane & 15;

    int bid = blockIdx.x;
    int cpx = nwg >> 3;
    int tile = (bid & 7) * cpx + (bid >> 3);
    int dir  = tile >= halfTiles;
    int lt   = dir ? (tile - halfTiles) : tile;
    int row0 = (lt >> 3) * 128;
    int n0   = (lt & 7) * 128;
    const unsigned short* inp = dir ? inpB : inpF;
    const unsigned short* WT  = dir ? WTb : WTf;
    unsigned short* zt_out    = dir ? ATB : ATF;

    f32x4 acc[4][4];
    #pragma unroll
    for (int m = 0; m < 4; m++)
        #pragma unroll
        for (int n = 0; n < 4; n++) acc[m][n] = (f32x4){0.f,0.f,0.f,0.f};

    // staging slots: u0 = tid, u1 = tid+256; global src permuted to match
    int u0 = tid, u1 = tid + 256;
    int ar0 = ((u0 >> 6) << 4) | (u0 & 15);  int ac0 = (u0 >> 4) & 3;
    int ar1 = ((u1 >> 6) << 4) | (u1 & 15);  int ac1 = (u1 >> 4) & 3;
    const unsigned short* aSrc0 = &inp[(size_t)(row0 + ar0)*H_ + ac0*8];
    const unsigned short* aSrc1 = &inp[(size_t)(row0 + ar1)*H_ + ac1*8];
    const unsigned short* bSrc0 = &WT [(size_t)(n0   + ar0)*H_ + ac0*8];
    const unsigned short* bSrc1 = &WT [(size_t)(n0   + ar1)*H_ + ac1*8];

    uint4 vA0 = *(const uint4*)aSrc0;
    uint4 vA1 = *(const uint4*)aSrc1;
    uint4 vB0 = *(const uint4*)bSrc0;
    uint4 vB1 = *(const uint4*)bSrc1;

    for (int k0 = 0; k0 < H_; k0 += 32) {
        __syncthreads();
        As2[u0] = vA0; As2[u1] = vA1;
        Bs2[u0] = vB0; Bs2[u1] = vB1;
        __syncthreads();
        if (k0 + 32 < H_) {
            vA0 = *(const uint4*)(aSrc0 + k0 + 32);
            vA1 = *(const uint4*)(aSrc1 + k0 + 32);
            vB0 = *(const uint4*)(bSrc0 + k0 + 32);
            vB1 = *(const uint4*)(bSrc1 + k0 + 32);
        }
        bf16x8 af[4], bf[4];
        #pragma unroll
        for (int m = 0; m < 4; m++)
            af[m] = *(const bf16x8*)&As2[(wm*4 + m)*64 + lane];
        #pragma unroll
        for (int n = 0; n < 4; n++)
            bf[n] = *(const bf16x8*)&Bs2[(wn*4 + n)*64 + lane];
        #pragma unroll
        for (int m = 0; m < 4; m++)
            #pragma unroll
            for (int n = 0; n < 4; n++)
                acc[m][n] = __builtin_amdgcn_mfma_f32_16x16x32_bf16(af[m], bf[n], acc[m][n], 0, 0, 0);
    }

    #pragma unroll
    for (int m = 0; m < 4; m++)
        #pragma unroll
        for (int n = 0; n < 4; n++) {
            int colg = n0 + wn*64 + n*16 + lr;
            #pragma unroll
            for (int r = 0; r < 4; r++) {
                int rowg = row0 + wm*64 + m*16 + kg*4 + r;
                zt_out[(size_t)rowg*NWS_ + colg] = f2b(acc[m][n][r]);
            }
        }
}

// ---------------------------------------------------------------------------
// K4a: bias + activations + chunked scan pass A, in place on AT rows.
// ---------------------------------------------------------------------------
__global__ __launch_bounds__(256) void k4a(
    unsigned short* __restrict__ ATF, unsigned short* __restrict__ ATB,
    const float* __restrict__ bzf, const float* __restrict__ bhf,
    const float* __restrict__ bzb, const float* __restrict__ bhb,
    float* __restrict__ Scar, float* __restrict__ Pcar, int nb)
{
    int g = blockIdx.x*256 + threadIdx.x;
    int col   = g & (H_-1);
    int chunk = (g >> 9) & (CH_-1);
    int rest  = g >> 13;
    int bb    = rest % nb;
    int dir   = rest / nb;
    unsigned short* AT = dir ? ATB : ATF;
    float bzv = (dir ? bzb : bzf)[col];
    float bhv = (dir ? bhb : bhf)[col];
    size_t base = (size_t)bb * L_ * NWS_ + col;
    float h = 0.f, pp = 1.f;
    if (dir == 0) {
        int lo = chunk * CL_;
        for (int p = 0; p < CL_; p += 8) {
            unsigned short zv[8], hv[8];
            #pragma unroll
            for (int j = 0; j < 8; j++) {
                size_t idx = base + (size_t)(lo+p+j)*NWS_;
                zv[j] = AT[idx]; hv[j] = AT[idx + H_];
            }
            #pragma unroll
            for (int j = 0; j < 8; j++) {
                size_t idx = base + (size_t)(lo+p+j)*NWS_;
                float zg = sigmoid_f(b2f(zv[j]) + bzv);
                float a  = 1.f - zg;
                float bg = zg * tanh_f(b2f(hv[j]) + bhv);
                AT[idx]      = f2b(h);
                AT[idx + H_] = f2b(pp);
                h = fmaf(a, h, bg);
                pp *= a;
            }
        }
    } else {
        int hi = chunk * CL_ + CL_ - 1;
        for (int p = 0; p < CL_; p += 8) {
            unsigned short zv[8], hv[8];
            #pragma unroll
            for (int j = 0; j < 8; j++) {
                size_t idx = base + (size_t)(hi-p-j)*NWS_;
                zv[j] = AT[idx]; hv[j] = AT[idx + H_];
            }
            #pragma unroll
            for (int j = 0; j < 8; j++) {
                size_t idx = base + (size_t)(hi-p-j)*NWS_;
                float zg = sigmoid_f(b2f(zv[j]) + bzv);
                float a  = 1.f - zg;
                float bg = zg * tanh_f(b2f(hv[j]) + bhv);
                AT[idx]      = f2b(h);
                AT[idx + H_] = f2b(pp);
                h = fmaf(a, h, bg);
                pp *= a;
            }
        }
    }
    int ci = ((dir*nb + bb)*CH_ + chunk)*H_ + col;
    Scar[ci] = h; Pcar[ci] = pp;
}

// K4b: chain carries across chunks.
__global__ __launch_bounds__(256) void k4b(
    const float* __restrict__ Scar, const float* __restrict__ Pcar,
    float* __restrict__ Hstart, int nb)
{
    int g = blockIdx.x*256 + threadIdx.x;
    int col  = g & (H_-1);
    int rest = g >> 9;
    int bb   = rest % nb;
    int dir  = rest / nb;
    int baseci = (dir*nb + bb)*CH_;
    float h = 0.f;
    if (dir == 0) {
        for (int c = 0; c < CH_; c++) {
            int ci = (baseci + c)*H_ + col;
            Hstart[ci] = h;
            h = Scar[ci] + Pcar[ci]*h;
        }
    } else {
        for (int c = CH_-1; c >= 0; c--) {
            int ci = (baseci + c)*H_ + col;
            Hstart[ci] = h;
            h = Scar[ci] + Pcar[ci]*h;
        }
    }
}

// ---------------------------------------------------------------------------
// K5 fused: LN (rolling-1 prefetch) -> XOR-swizzled LDS A, barrier-free head
// GEMM (3-deep B register pipeline), gelu*Wg2 + shfl row-reduce.
// __launch_bounds__(256,2): keep pipelines live in registers (round-15 win).
// ---------------------------------------------------------------------------
__global__ __launch_bounds__(256, 2) void k5_fused(
    const unsigned short* __restrict__ ATF, const unsigned short* __restrict__ ATB,
    const float* __restrict__ Hstart,
    const float* __restrict__ tenc,
    const float* __restrict__ ln_g, const float* __restrict__ ln_b,
    const float* __restrict__ tsp,
    const uint4* __restrict__ P,              // [33*1024] packed Wg1 fragments
    const float* __restrict__ bg1, const float* __restrict__ Wg2,
    const float* __restrict__ bg2,
    float* __restrict__ out, int nb)
{
    __shared__ __align__(16) unsigned short A[RB5_*ASTR_];   // 68 KB
    __shared__ float red[4][RB5_];
    int tid = threadIdx.x, lane = tid & 63, wv = tid >> 6;
    int kg = lane >> 4, lr = lane & 15;
    int row0 = blockIdx.x * RB5_;
    float ts = tsp[0];

    int bb    = row0 >> 11;          // / L_
    int chunk = (row0 & (L_-1)) >> 7;
    int cif = (bb*CH_ + chunk)*H_;
    int cib = ((nb + bb)*CH_ + chunk)*H_;
    int c0 = lane*8;
    float4 hfa = *(const float4*)&Hstart[cif + c0];
    float4 hfb = *(const float4*)&Hstart[cif + c0 + 4];
    float4 hba = *(const float4*)&Hstart[cib + c0];
    float4 hbb = *(const float4*)&Hstart[cib + c0 + 4];
    float h0f[8] = {hfa.x,hfa.y,hfa.z,hfa.w,hfb.x,hfb.y,hfb.z,hfb.w};
    float h0b[8] = {hba.x,hba.y,hba.z,hba.w,hbb.x,hbb.y,hbb.z,hbb.w};

    float gf[8], bf_[8], gb_[8], bb_[8];
    #pragma unroll
    for (int j = 0; j < 8; j++) {
        gf[j]  = ln_g[c0+j];     bf_[j] = ln_b[c0+j];
        gb_[j] = ln_g[H_+c0+j];  bb_[j] = ln_b[H_+c0+j];
    }
    float gt = 0.f, bt = 0.f;
    if (lane < NT_) { gt = ln_g[2*H_+lane]; bt = ln_b[2*H_+lane]; }

    // ---- LN phase with rolling-1 row prefetch ----
    size_t rowBase = (size_t)(row0 + wv*8) * NWS_;
    uint4 cSF = *(const uint4*)&ATF[rowBase + c0];
    uint4 cPF = *(const uint4*)&ATF[rowBase + H_ + c0];
    uint4 cSB = *(const uint4*)&ATB[rowBase + c0];
    uint4 cPB = *(const uint4*)&ATB[rowBase + H_ + c0];

    #pragma unroll
    for (int i = 0; i < 8; i++) {
        int r = wv*8 + i;
        size_t row = (size_t)row0 + r;
        uint4 SF = cSF, PF = cPF, SB = cSB, PB = cPB;
        if (i < 7) {
            size_t rb2 = rowBase + (size_t)(i+1)*NWS_;
            cSF = *(const uint4*)&ATF[rb2 + c0];
            cPF = *(const uint4*)&ATF[rb2 + H_ + c0];
            cSB = *(const uint4*)&ATB[rb2 + c0];
            cPB = *(const uint4*)&ATB[rb2 + H_ + c0];
        }
        const unsigned short* sf = (const unsigned short*)&SF;
        const unsigned short* pf = (const unsigned short*)&PF;
        const unsigned short* sb = (const unsigned short*)&SB;
        const unsigned short* pb = (const unsigned short*)&PB;
        float fv[8], bv[8];
        float S = 0.f, Q = 0.f;
        #pragma unroll
        for (int j = 0; j < 8; j++) {
            fv[j] = fmaf(b2f(pf[j]), h0f[j], b2f(sf[j]));
            S += fv[j]; Q += fv[j]*fv[j];
            bv[j] = fmaf(b2f(pb[j]), h0b[j], b2f(sb[j]));
            S += bv[j]; Q += bv[j]*bv[j];
        }
        float tv = 0.f;
        if (lane < NT_) { tv = tenc[row*NT_ + lane]; S += tv; Q += tv*tv; }
        #pragma unroll
        for (int off = 32; off > 0; off >>= 1) {
            S += __shfl_xor(S, off, 64);
            Q += __shfl_xor(Q, off, 64);
        }
        float mu = S * (1.f/1032.f);
        float rs = rsqrtf(Q * (1.f/1032.f) - mu*mu + 1e-5f);
        int key = r & 7;
        unsigned short o[8];
        #pragma unroll
        for (int j = 0; j < 8; j++) o[j] = f2b((fv[j]-mu)*rs*gf[j] + bf_[j]);
        *(uint4*)&A[r*ASTR_ + ((lane ^ key)*8)] = *(const uint4*)o;
        #pragma unroll
        for (int j = 0; j < 8; j++) o[j] = f2b((bv[j]-mu)*rs*gb_[j] + bb_[j]);
        *(uint4*)&A[r*ASTR_ + (((64+lane) ^ key)*8)] = *(const uint4*)o;
        if (lane < NT_) {
            A[r*ASTR_ + ((128 ^ key)*8) + lane] =
                f2b(((tv-mu)*rs*gt + bt) * ts);
        } else {
            int cc = 128 + (lane >> 3);
            A[r*ASTR_ + ((cc ^ key)*8) + (lane & 7)] = 0;
        }
    }
    __syncthreads();

    // ---- GEMM phase (no barriers, 3-deep B pipeline) ----
    f32x4 acc[2][4];
    #pragma unroll
    for (int m = 0; m < 2; m++)
        #pragma unroll
        for (int n = 0; n < 4; n++) acc[m][n] = (f32x4){0.f,0.f,0.f,0.f};

    const uint4* Pw = P + wv*256 + lr*4 + kg;
    int keyA = lr & 7;

#define LOADB(v0,v1,v2,v3,KB) do { \
        const uint4* q_ = Pw + (KB)*1024; \
        v0 = *(const bf16x8*)&q_[0]; \
        v1 = *(const bf16x8*)&q_[64]; \
        v2 = *(const bf16x8*)&q_[128]; \
        v3 = *(const bf16x8*)&q_[192]; \
    } while(0)
#define LDSA0(KB) (*(const bf16x8*)&A[lr*ASTR_      + ((((KB)*4+kg) ^ keyA)*8)])
#define LDSA1(KB) (*(const bf16x8*)&A[(16+lr)*ASTR_ + ((((KB)*4+kg) ^ keyA)*8)])
#define MFMA8(v0,v1,v2,v3,a0_,a1_) do { \
        acc[0][0] = __builtin_amdgcn_mfma_f32_16x16x32_bf16(a0_, v0, acc[0][0],0,0,0); \
        acc[0][1] = __builtin_amdgcn_mfma_f32_16x16x32_bf16(a0_, v1, acc[0][1],0,0,0); \
        acc[0][2] = __builtin_amdgcn_mfma_f32_16x16x32_bf16(a0_, v2, acc[0][2],0,0,0); \
        acc[0][3] = __builtin_amdgcn_mfma_f32_16x16x32_bf16(a0_, v3, acc[0][3],0,0,0); \
        acc[1][0] = __builtin_amdgcn_mfma_f32_16x16x32_bf16(a1_, v0, acc[1][0],0,0,0); \
        acc[1][1] = __builtin_amdgcn_mfma_f32_16x16x32_bf16(a1_, v1, acc[1][1],0,0,0); \
        acc[1][2] = __builtin_amdgcn_mfma_f32_16x16x32_bf16(a1_, v2, acc[1][2],0,0,0); \
        acc[1][3] = __builtin_amdgcn_mfma_f32_16x16x32_bf16(a1_, v3, acc[1][3],0,0,0); \
    } while(0)

    bf16x8 a0,a1,a2,a3, d0,d1,d2,d3, e0,e1,e2,e3;
    LOADB(a0,a1,a2,a3, 0);
    LOADB(d0,d1,d2,d3, 1);
    LOADB(e0,e1,e2,e3, 2);
    for (int kb = 0; kb < 30; kb += 3) {
        bf16x8 af0, af1;
        af0 = LDSA0(kb);   af1 = LDSA1(kb);
        MFMA8(a0,a1,a2,a3, af0, af1);
        LOADB(a0,a1,a2,a3, kb+3);
        af0 = LDSA0(kb+1); af1 = LDSA1(kb+1);
        MFMA8(d0,d1,d2,d3, af0, af1);
        LOADB(d0,d1,d2,d3, kb+4);
        af0 = LDSA0(kb+2); af1 = LDSA1(kb+2);
        MFMA8(e0,e1,e2,e3, af0, af1);
        LOADB(e0,e1,e2,e3, kb+5);
    }
    {
        bf16x8 af0, af1;
        af0 = LDSA0(30); af1 = LDSA1(30);
        MFMA8(a0,a1,a2,a3, af0, af1);
        af0 = LDSA0(31); af1 = LDSA1(31);
        MFMA8(d0,d1,d2,d3, af0, af1);
        af0 = LDSA0(32); af1 = LDSA1(32);
        MFMA8(e0,e1,e2,e3, af0, af1);
    }
#undef LOADB
#undef LDSA0
#undef LDSA1
#undef MFMA8

    // ---- epilogue: gelu + *Wg2, reduce over this wave's 64 cols ----
    float rsum[2][4] = {{0.f,0.f,0.f,0.f},{0.f,0.f,0.f,0.f}};
    #pragma unroll
    for (int n = 0; n < 4; n++) {
        int colg = wv*64 + n*16 + lr;
        float bgv = bg1[colg], w2v = Wg2[colg];
        #pragma unroll
        for (int m = 0; m < 2; m++)
            #pragma unroll
            for (int r = 0; r < 4; r++) {
                float gv = gelu_f(acc[m][n][r] + bgv);
                rsum[m][r] = fmaf(gv, w2v, rsum[m][r]);
            }
    }
    #pragma unroll
    for (int off = 1; off < 16; off <<= 1)
        #pragma unroll
        for (int m = 0; m < 2; m++)
            #pragma unroll
            for (int r = 0; r < 4; r++)
                rsum[m][r] += __shfl_xor(rsum[m][r], off, 64);
    if (lr == 0) {
        #pragma unroll
        for (int m = 0; m < 2; m++)
            #pragma unroll
            for (int r = 0; r < 4; r++)
                red[wv][m*16 + kg*4 + r] = rsum[m][r];
    }
    __syncthreads();
    if (tid < RB5_)
        out[row0 + tid] = red[0][tid] + red[1][tid] + red[2][tid] + red[3][tid] + bg2[0];
}

// ---------------------------------------------------------------------------
extern "C" void kernel_launch(void* const* d_in, const int* in_sizes, int n_in,
                              void* d_out, int out_size, void* d_ws, size_t ws_size,
                              hipStream_t stream)
{
    const float* x    = (const float*)d_in[0];
    const float* t    = (const float*)d_in[1];
    const float* Wt1  = (const float*)d_in[2];
    const float* bt1  = (const float*)d_in[3];
    const float* Wt2  = (const float*)d_in[4];
    const float* bt2  = (const float*)d_in[5];
    const float* Wpf  = (const float*)d_in[6];
    const float* bpf  = (const float*)d_in[7];
    const float* Wpb  = (const float*)d_in[8];
    const float* bpb  = (const float*)d_in[9];
    const float* Wzf  = (const float*)d_in[10];
    const float* bzf  = (const float*)d_in[11];
    const float* Whf  = (const float*)d_in[12];
    const float* bhf  = (const float*)d_in[13];
    const float* Wzb  = (const float*)d_in[14];
    const float* bzb  = (const float*)d_in[15];
    const float* Whb  = (const float*)d_in[16];
    const float* bhb  = (const float*)d_in[17];
    const float* ln_g = (const float*)d_in[18];
    const float* ln_b = (const float*)d_in[19];
    const float* tsc  = (const float*)d_in[20];
    const float* Wg1  = (const float*)d_in[21];
    const float* bg1  = (const float*)d_in[22];
    const float* Wg2  = (const float*)d_in[23];
    const float* bg2  = (const float*)d_in[24];
    float* out = (float*)d_out;

    char* p = (char*)d_ws;
    auto carve = [&](size_t bytes) -> char* {
        char* q = p; p += (bytes + 255) & ~(size_t)255; return q;
    };

    unsigned short* WTf = (unsigned short*)carve((size_t)2*H_*H_*2);
    unsigned short* WTb = (unsigned short*)carve((size_t)2*H_*H_*2);
    uint4*          Pg  = (uint4*)carve((size_t)33*1024*16);

    const size_t perBatch = (size_t)L_*H_*2*2          // inpF + inpB
                          + (size_t)L_*NWS_*2*2        // ATF + ATB
                          + (size_t)L_*NT_*4           // tenc
                          + (size_t)CH_*H_*4*3*2;      // carries
    size_t fixedUsed = (size_t)(p - (char*)d_ws) + 64*1024;
    int NB = B_;
    while (NB > 1 && fixedUsed + (size_t)NB*perBatch > ws_size) NB >>= 1;

    unsigned short* inpF = (unsigned short*)carve((size_t)NB*L_*H_*2);
    unsigned short* inpB = (unsigned short*)carve((size_t)NB*L_*H_*2);
    unsigned short* ATF = (unsigned short*)carve((size_t)NB*L_*NWS_*2);
    unsigned short* ATB = (unsigned short*)carve((size_t)NB*L_*NWS_*2);
    float* tenc   = (float*)carve((size_t)NB*L_*NT_*4);
    float* Scar   = (float*)carve((size_t)2*NB*CH_*H_*4);
    float* Pcar   = (float*)carve((size_t)2*NB*CH_*H_*4);
    float* Hstart = (float*)carve((size_t)2*NB*CH_*H_*4);

    {
        dim3 g(H_/32, H_/32);
        kT<<<g, 256, 0, stream>>>(Wzf, WTf,         H_, H_, H_);
        kT<<<g, 256, 0, stream>>>(Whf, WTf + H_*H_, H_, H_, H_);
        kT<<<g, 256, 0, stream>>>(Wzb, WTb,         H_, H_, H_);
        kT<<<g, 256, 0, stream>>>(Whb, WTb + H_*H_, H_, H_, H_);
        kP<<<132, 256, 0, stream>>>(Wg1, Pg);
    }

    for (int b0 = 0; b0 < B_; b0 += NB) {
        int rows = NB * L_;
        int halfTiles = (rows/128) * 8;
        int nwg3 = 2 * halfTiles;

        k1_tenc_inp<<<rows/4, 256, 0, stream>>>(
            x + (size_t)b0*L_*2, t + (size_t)b0*L_,
            Wt1, bt1, Wt2, bt2, Wpf, bpf, Wpb, bpb,
            tenc, inpF, inpB);

        k3g<<<nwg3, 256, 0, stream>>>(inpF, inpB, WTf, WTb, ATF, ATB,
                                      nwg3, halfTiles);

        int scanThreads = 2*NB*H_*CH_;
        k4a<<<scanThreads/256, 256, 0, stream>>>(ATF, ATB, bzf, bhf, bzb, bhb,
                                                 Scar, Pcar, NB);
        k4b<<<(2*NB*H_)/256, 256, 0, stream>>>(Scar, Pcar, Hstart, NB);

        k5_fused<<<rows/RB5_, 256, 0, stream>>>(
            ATF, ATB, Hstart, tenc, ln_g, ln_b, tsc,
            Pg, bg1, Wg2, bg2, out + (size_t)b0*L_, NB);
    }
}

// Round 17
// 289.014 us; speedup vs baseline: 1.0755x; 1.0755x over previous
//
#include <hip/hip_runtime.h>
#include <hip/hip_bf16.h>
#include <math.h>

#define B_    16
#define L_    2048
#define H_    512
#define NT_   8
#define OUT_  1032
#define HEAD_ 256
#define CH_   16
#define CL_   (L_/CH_)   // 128
#define NWS_  1152       // AT row stride in shorts (z|h -> S|PP in place)

// k5 A-LDS geometry: 32 rows, 136 chunks of 16B (2176B row), XOR-swizzled
#define ACH_  136
#define ASTR_ (ACH_*8)   // shorts per row = 1088
#define RB5_  32         // rows per k5 block

typedef short bf16x8 __attribute__((ext_vector_type(8)));
typedef float f32x4  __attribute__((ext_vector_type(4)));

__device__ __forceinline__ float b2f(unsigned short u) {
    union { unsigned int u32; float f; } v; v.u32 = ((unsigned int)u) << 16; return v.f;
}
__device__ __forceinline__ unsigned short f2b(float f) {
    __hip_bfloat16 h = __float2bfloat16(f);
    return *reinterpret_cast<unsigned short*>(&h);
}
__device__ __forceinline__ float sigmoid_f(float x) {
    return 1.f / (1.f + exp2f(-1.44269504f * x));
}
__device__ __forceinline__ float tanh_f(float x) {
    float e = exp2f(2.88539008f * x);
    return 1.f - 2.f / (e + 1.f);
}
__device__ __forceinline__ float gelu_f(float g) {
    float u  = 0.70710678118654752f * g;
    float ax = fabsf(u);
    float t  = 1.f / (1.f + 0.3275911f * ax);
    float poly = ((((1.061405429f*t - 1.453152027f)*t + 1.421413741f)*t
                   - 0.284496736f)*t + 0.254829592f)*t;
    float e  = exp2f(-1.44269504f * ax * ax);
    float er = 1.f - poly * e;
    er = (u < 0.f) ? -er : er;
    return 0.5f * g * (1.f + er);
}

// ---------------------------------------------------------------------------
// kT: transpose + f32->bf16. in f32 [R][C] -> out bf16 [C][RP], zero r>=R.
// ---------------------------------------------------------------------------
__global__ __launch_bounds__(256) void kT(const float* __restrict__ in,
                                          unsigned short* __restrict__ out,
                                          int R, int C, int RP)
{
    __shared__ float tile[32][33];
    int c0 = blockIdx.x * 32, r0 = blockIdx.y * 32;
    int tx = threadIdx.x & 31, ty = threadIdx.x >> 5;
    #pragma unroll
    for (int j = 0; j < 32; j += 8) {
        int r = r0 + ty + j, c = c0 + tx;
        tile[ty + j][tx] = (r < R && c < C) ? in[(size_t)r*C + c] : 0.f;
    }
    __syncthreads();
    #pragma unroll
    for (int j = 0; j < 32; j += 8) {
        int c = c0 + ty + j, r = r0 + tx;
        if (c < C && r < RP) out[(size_t)c*RP + r] = f2b(tile[tx][ty + j]);
    }
}

// ---------------------------------------------------------------------------
// kP: pack Wg1 (f32 [OUT_][256]) into MFMA B-fragment chunks, 33 K-blocks.
// ---------------------------------------------------------------------------
__global__ __launch_bounds__(256) void kP(const float* __restrict__ Wg1,
                                          uint4* __restrict__ P)
{
    int idx = blockIdx.x*256 + threadIdx.x;
    if (idx >= 33*1024) return;
    int kb = idx >> 10;
    int rem = idx & 1023;
    int c  = rem >> 2;
    int kg = rem & 3;
    int k0 = kb*32 + kg*8;
    unsigned short o[8];
    #pragma unroll
    for (int j = 0; j < 8; j++) {
        int k = k0 + j;
        o[j] = (k < OUT_) ? f2b(Wg1[(size_t)k*HEAD_ + c]) : (unsigned short)0;
    }
    P[idx] = *(const uint4*)o;
}

// ---------------------------------------------------------------------------
// K1 (both dirs): t_enc MLP + inp_{f,b} = xc @ Wp{f,b} + bp{f,b}. wave-per-row.
// ---------------------------------------------------------------------------
__global__ __launch_bounds__(256) void k1_tenc_inp(
    const float* __restrict__ x, const float* __restrict__ t,
    const float* __restrict__ Wt1, const float* __restrict__ bt1,
    const float* __restrict__ Wt2, const float* __restrict__ bt2,
    const float* __restrict__ Wpf, const float* __restrict__ bpf,
    const float* __restrict__ Wpb, const float* __restrict__ bpb,
    float* __restrict__ t_enc,
    unsigned short* __restrict__ inp_f, unsigned short* __restrict__ inp_b)
{
    int wv = threadIdx.x >> 6, lane = threadIdx.x & 63;
    size_t row = (size_t)blockIdx.x*4 + wv;
    float tv = t[row];
    float r1[NT_], te[NT_];
    #pragma unroll
    for (int k = 0; k < NT_; k++) r1[k] = fmaxf(tv*Wt1[k] + bt1[k], 0.f);
    #pragma unroll
    for (int j = 0; j < NT_; j++) {
        float a = bt2[j];
        #pragma unroll
        for (int k = 0; k < NT_; k++) a = fmaf(r1[k], Wt2[k*NT_+j], a);
        te[j] = a;
    }
    if (lane < NT_) t_enc[row*NT_ + lane] = te[lane];
    float x0 = x[row*2+0], x1 = x[row*2+1];
    int c0 = lane*8;
    float af[8], ab[8];
    #pragma unroll
    for (int j = 0; j < 8; j++) {
        int c = c0 + j;
        af[j] = fmaf(x0, Wpf[c], fmaf(x1, Wpf[H_+c], bpf[c]));
        ab[j] = fmaf(x0, Wpb[c], fmaf(x1, Wpb[H_+c], bpb[c]));
    }
    #pragma unroll
    for (int k = 0; k < NT_; k++) {
        #pragma unroll
        for (int j = 0; j < 8; j++) {
            af[j] = fmaf(te[k], Wpf[(2+k)*H_+c0+j], af[j]);
            ab[j] = fmaf(te[k], Wpb[(2+k)*H_+c0+j], ab[j]);
        }
    }
    unsigned short of[8], ob[8];
    #pragma unroll
    for (int j = 0; j < 8; j++) { of[j] = f2b(af[j]); ob[j] = f2b(ab[j]); }
    *(uint4*)&inp_f[row*H_ + c0] = *(const uint4*)of;
    *(uint4*)&inp_b[row*H_ + c0] = *(const uint4*)ob;
}

// ---------------------------------------------------------------------------
// K3g (both dirs): AT{F,B}[row][0..1023] = inp{f,b} @ [Wz|Wh].
// Round-15 proven body (128x128 tile, BK=32, 80B-pad LDS, register prefetch,
// XCD remap). NEW epilogue: transpose acc through LDS (reuse As) so global
// stores are 32B-contiguous uint4 pairs completing full 64B lines
// (fixes the 2x write amplification of scattered 2B stores).
// ---------------------------------------------------------------------------
__global__ __launch_bounds__(256) void k3g(
    const unsigned short* __restrict__ inpF,
    const unsigned short* __restrict__ inpB,
    const unsigned short* __restrict__ WTf,   // [1024][512] (Wz rows, Wh rows)
    const unsigned short* __restrict__ WTb,
    unsigned short* __restrict__ ATF,
    unsigned short* __restrict__ ATB,
    int nwg, int halfTiles)
{
    __shared__ __align__(16) unsigned short As[128*40];
    __shared__ __align__(16) unsigned short Bs[128*40];
    int tid = threadIdx.x;
    int lane = tid & 63, w = tid >> 6;
    int wm = w >> 1, wn = w & 1;
    int kg = lane >> 4, lr = lane & 15;

    int bid = blockIdx.x;
    int cpx = nwg >> 3;
    int tile = (bid & 7) * cpx + (bid >> 3);
    int dir  = tile >= halfTiles;
    int lt   = dir ? (tile - halfTiles) : tile;
    int row0 = (lt >> 3) * 128;
    int n0   = (lt & 7) * 128;
    const unsigned short* inp = dir ? inpB : inpF;
    const unsigned short* WT  = dir ? WTb : WTf;
    unsigned short* zt_out    = dir ? ATB : ATF;

    f32x4 acc[4][4];
    #pragma unroll
    for (int m = 0; m < 4; m++)
        #pragma unroll
        for (int n = 0; n < 4; n++) acc[m][n] = (f32x4){0.f,0.f,0.f,0.f};

    int ar = tid >> 1, aseg = tid & 1;

    uint4 va0, va1, vb0, vb1;
    {
        const uint4* ga = (const uint4*)&inp[(size_t)(row0+ar)*H_ + aseg*16];
        va0 = ga[0]; va1 = ga[1];
        const uint4* gb = (const uint4*)&WT[(size_t)(n0+ar)*H_ + aseg*16];
        vb0 = gb[0]; vb1 = gb[1];
    }

    for (int k0 = 0; k0 < H_; k0 += 32) {
        __syncthreads();
        *(uint4*)&As[ar*40 + aseg*16]     = va0;
        *(uint4*)&As[ar*40 + aseg*16 + 8] = va1;
        *(uint4*)&Bs[ar*40 + aseg*16]     = vb0;
        *(uint4*)&Bs[ar*40 + aseg*16 + 8] = vb1;
        __syncthreads();
        if (k0 + 32 < H_) {
            const uint4* ga = (const uint4*)&inp[(size_t)(row0+ar)*H_ + k0+32 + aseg*16];
            va0 = ga[0]; va1 = ga[1];
            const uint4* gb = (const uint4*)&WT[(size_t)(n0+ar)*H_ + k0+32 + aseg*16];
            vb0 = gb[0]; vb1 = gb[1];
        }
        bf16x8 af[4], bf[4];
        #pragma unroll
        for (int m = 0; m < 4; m++)
            af[m] = *(const bf16x8*)&As[(wm*64 + m*16 + lr)*40 + kg*8];
        #pragma unroll
        for (int n = 0; n < 4; n++)
            bf[n] = *(const bf16x8*)&Bs[(wn*64 + n*16 + lr)*40 + kg*8];
        #pragma unroll
        for (int m = 0; m < 4; m++)
            #pragma unroll
            for (int n = 0; n < 4; n++)
                acc[m][n] = __builtin_amdgcn_mfma_f32_16x16x32_bf16(af[m], bf[n], acc[m][n], 0, 0, 0);
    }

    // ---- epilogue: LDS-transposed coalesced stores (4 passes of 32 cols) ----
    unsigned short* Cs = As;    // reuse (dead after K-loop); 128*40 shorts
    #pragma unroll
    for (int p = 0; p < 4; p++) {
        __syncthreads();
        if (wn == (p >> 1)) {
            int ng = (p & 1) * 2;
            #pragma unroll
            for (int nn = 0; nn < 2; nn++) {
                #pragma unroll
                for (int m = 0; m < 4; m++) {
                    int rl = wm*64 + m*16 + kg*4;
                    int cl = nn*16 + lr;
                    #pragma unroll
                    for (int r = 0; r < 4; r++)
                        Cs[(rl + r)*40 + cl] = f2b(acc[m][ng+nn][r]);
                }
            }
        }
        __syncthreads();
        int rr = tid >> 1, seg = tid & 1;
        uint4 v0 = *(const uint4*)&Cs[rr*40 + seg*16];
        uint4 v1 = *(const uint4*)&Cs[rr*40 + seg*16 + 8];
        uint4* dst = (uint4*)&zt_out[(size_t)(row0 + rr)*NWS_ + n0 + p*32 + seg*16];
        dst[0] = v0; dst[1] = v1;
    }
}

// ---------------------------------------------------------------------------
// K4a: bias + activations + chunked scan pass A, in place on AT rows.
// ---------------------------------------------------------------------------
__global__ __launch_bounds__(256) void k4a(
    unsigned short* __restrict__ ATF, unsigned short* __restrict__ ATB,
    const float* __restrict__ bzf, const float* __restrict__ bhf,
    const float* __restrict__ bzb, const float* __restrict__ bhb,
    float* __restrict__ Scar, float* __restrict__ Pcar, int nb)
{
    int g = blockIdx.x*256 + threadIdx.x;
    int col   = g & (H_-1);
    int chunk = (g >> 9) & (CH_-1);
    int rest  = g >> 13;
    int bb    = rest % nb;
    int dir   = rest / nb;
    unsigned short* AT = dir ? ATB : ATF;
    float bzv = (dir ? bzb : bzf)[col];
    float bhv = (dir ? bhb : bhf)[col];
    size_t base = (size_t)bb * L_ * NWS_ + col;
    float h = 0.f, pp = 1.f;
    if (dir == 0) {
        int lo = chunk * CL_;
        for (int p = 0; p < CL_; p += 8) {
            unsigned short zv[8], hv[8];
            #pragma unroll
            for (int j = 0; j < 8; j++) {
                size_t idx = base + (size_t)(lo+p+j)*NWS_;
                zv[j] = AT[idx]; hv[j] = AT[idx + H_];
            }
            #pragma unroll
            for (int j = 0; j < 8; j++) {
                size_t idx = base + (size_t)(lo+p+j)*NWS_;
                float zg = sigmoid_f(b2f(zv[j]) + bzv);
                float a  = 1.f - zg;
                float bg = zg * tanh_f(b2f(hv[j]) + bhv);
                AT[idx]      = f2b(h);
                AT[idx + H_] = f2b(pp);
                h = fmaf(a, h, bg);
                pp *= a;
            }
        }
    } else {
        int hi = chunk * CL_ + CL_ - 1;
        for (int p = 0; p < CL_; p += 8) {
            unsigned short zv[8], hv[8];
            #pragma unroll
            for (int j = 0; j < 8; j++) {
                size_t idx = base + (size_t)(hi-p-j)*NWS_;
                zv[j] = AT[idx]; hv[j] = AT[idx + H_];
            }
            #pragma unroll
            for (int j = 0; j < 8; j++) {
                size_t idx = base + (size_t)(hi-p-j)*NWS_;
                float zg = sigmoid_f(b2f(zv[j]) + bzv);
                float a  = 1.f - zg;
                float bg = zg * tanh_f(b2f(hv[j]) + bhv);
                AT[idx]      = f2b(h);
                AT[idx + H_] = f2b(pp);
                h = fmaf(a, h, bg);
                pp *= a;
            }
        }
    }
    int ci = ((dir*nb + bb)*CH_ + chunk)*H_ + col;
    Scar[ci] = h; Pcar[ci] = pp;
}

// K4b: chain carries across chunks.
__global__ __launch_bounds__(256) void k4b(
    const float* __restrict__ Scar, const float* __restrict__ Pcar,
    float* __restrict__ Hstart, int nb)
{
    int g = blockIdx.x*256 + threadIdx.x;
    int col  = g & (H_-1);
    int rest = g >> 9;
    int bb   = rest % nb;
    int dir  = rest / nb;
    int baseci = (dir*nb + bb)*CH_;
    float h = 0.f;
    if (dir == 0) {
        for (int c = 0; c < CH_; c++) {
            int ci = (baseci + c)*H_ + col;
            Hstart[ci] = h;
            h = Scar[ci] + Pcar[ci]*h;
        }
    } else {
        for (int c = CH_-1; c >= 0; c--) {
            int ci = (baseci + c)*H_ + col;
            Hstart[ci] = h;
            h = Scar[ci] + Pcar[ci]*h;
        }
    }
}

// ---------------------------------------------------------------------------
// K5 fused: LN (rolling-1 prefetch) -> XOR-swizzled LDS A, barrier-free head
// GEMM (3-deep B register pipeline), gelu*Wg2 + shfl row-reduce.
// __launch_bounds__(256,2): keep pipelines live in registers (round-15 win).
// ---------------------------------------------------------------------------
__global__ __launch_bounds__(256, 2) void k5_fused(
    const unsigned short* __restrict__ ATF, const unsigned short* __restrict__ ATB,
    const float* __restrict__ Hstart,
    const float* __restrict__ tenc,
    const float* __restrict__ ln_g, const float* __restrict__ ln_b,
    const float* __restrict__ tsp,
    const uint4* __restrict__ P,              // [33*1024] packed Wg1 fragments
    const float* __restrict__ bg1, const float* __restrict__ Wg2,
    const float* __restrict__ bg2,
    float* __restrict__ out, int nb)
{
    __shared__ __align__(16) unsigned short A[RB5_*ASTR_];   // 68 KB
    __shared__ float red[4][RB5_];
    int tid = threadIdx.x, lane = tid & 63, wv = tid >> 6;
    int kg = lane >> 4, lr = lane & 15;
    int row0 = blockIdx.x * RB5_;
    float ts = tsp[0];

    int bb    = row0 >> 11;          // / L_
    int chunk = (row0 & (L_-1)) >> 7;
    int cif = (bb*CH_ + chunk)*H_;
    int cib = ((nb + bb)*CH_ + chunk)*H_;
    int c0 = lane*8;
    float4 hfa = *(const float4*)&Hstart[cif + c0];
    float4 hfb = *(const float4*)&Hstart[cif + c0 + 4];
    float4 hba = *(const float4*)&Hstart[cib + c0];
    float4 hbb = *(const float4*)&Hstart[cib + c0 + 4];
    float h0f[8] = {hfa.x,hfa.y,hfa.z,hfa.w,hfb.x,hfb.y,hfb.z,hfb.w};
    float h0b[8] = {hba.x,hba.y,hba.z,hba.w,hbb.x,hbb.y,hbb.z,hbb.w};

    float gf[8], bf_[8], gb_[8], bb_[8];
    #pragma unroll
    for (int j = 0; j < 8; j++) {
        gf[j]  = ln_g[c0+j];     bf_[j] = ln_b[c0+j];
        gb_[j] = ln_g[H_+c0+j];  bb_[j] = ln_b[H_+c0+j];
    }
    float gt = 0.f, bt = 0.f;
    if (lane < NT_) { gt = ln_g[2*H_+lane]; bt = ln_b[2*H_+lane]; }

    // ---- LN phase with rolling-1 row prefetch ----
    size_t rowBase = (size_t)(row0 + wv*8) * NWS_;
    uint4 cSF = *(const uint4*)&ATF[rowBase + c0];
    uint4 cPF = *(const uint4*)&ATF[rowBase + H_ + c0];
    uint4 cSB = *(const uint4*)&ATB[rowBase + c0];
    uint4 cPB = *(const uint4*)&ATB[rowBase + H_ + c0];

    #pragma unroll
    for (int i = 0; i < 8; i++) {
        int r = wv*8 + i;
        size_t row = (size_t)row0 + r;
        uint4 SF = cSF, PF = cPF, SB = cSB, PB = cPB;
        if (i < 7) {
            size_t rb2 = rowBase + (size_t)(i+1)*NWS_;
            cSF = *(const uint4*)&ATF[rb2 + c0];
            cPF = *(const uint4*)&ATF[rb2 + H_ + c0];
            cSB = *(const uint4*)&ATB[rb2 + c0];
            cPB = *(const uint4*)&ATB[rb2 + H_ + c0];
        }
        const unsigned short* sf = (const unsigned short*)&SF;
        const unsigned short* pf = (const unsigned short*)&PF;
        const unsigned short* sb = (const unsigned short*)&SB;
        const unsigned short* pb = (const unsigned short*)&PB;
        float fv[8], bv[8];
        float S = 0.f, Q = 0.f;
        #pragma unroll
        for (int j = 0; j < 8; j++) {
            fv[j] = fmaf(b2f(pf[j]), h0f[j], b2f(sf[j]));
            S += fv[j]; Q += fv[j]*fv[j];
            bv[j] = fmaf(b2f(pb[j]), h0b[j], b2f(sb[j]));
            S += bv[j]; Q += bv[j]*bv[j];
        }
        float tv = 0.f;
        if (lane < NT_) { tv = tenc[row*NT_ + lane]; S += tv; Q += tv*tv; }
        #pragma unroll
        for (int off = 32; off > 0; off >>= 1) {
            S += __shfl_xor(S, off, 64);
            Q += __shfl_xor(Q, off, 64);
        }
        float mu = S * (1.f/1032.f);
        float rs = rsqrtf(Q * (1.f/1032.f) - mu*mu + 1e-5f);
        int key = r & 7;
        unsigned short o[8];
        #pragma unroll
        for (int j = 0; j < 8; j++) o[j] = f2b((fv[j]-mu)*rs*gf[j] + bf_[j]);
        *(uint4*)&A[r*ASTR_ + ((lane ^ key)*8)] = *(const uint4*)o;
        #pragma unroll
        for (int j = 0; j < 8; j++) o[j] = f2b((bv[j]-mu)*rs*gb_[j] + bb_[j]);
        *(uint4*)&A[r*ASTR_ + (((64+lane) ^ key)*8)] = *(const uint4*)o;
        if (lane < NT_) {
            A[r*ASTR_ + ((128 ^ key)*8) + lane] =
                f2b(((tv-mu)*rs*gt + bt) * ts);
        } else {
            int cc = 128 + (lane >> 3);
            A[r*ASTR_ + ((cc ^ key)*8) + (lane & 7)] = 0;
        }
    }
    __syncthreads();

    // ---- GEMM phase (no barriers, 3-deep B pipeline) ----
    f32x4 acc[2][4];
    #pragma unroll
    for (int m = 0; m < 2; m++)
        #pragma unroll
        for (int n = 0; n < 4; n++) acc[m][n] = (f32x4){0.f,0.f,0.f,0.f};

    const uint4* Pw = P + wv*256 + lr*4 + kg;
    int keyA = lr & 7;

#define LOADB(v0,v1,v2,v3,KB) do { \
        const uint4* q_ = Pw + (KB)*1024; \
        v0 = *(const bf16x8*)&q_[0]; \
        v1 = *(const bf16x8*)&q_[64]; \
        v2 = *(const bf16x8*)&q_[128]; \
        v3 = *(const bf16x8*)&q_[192]; \
    } while(0)
#define LDSA0(KB) (*(const bf16x8*)&A[lr*ASTR_      + ((((KB)*4+kg) ^ keyA)*8)])
#define LDSA1(KB) (*(const bf16x8*)&A[(16+lr)*ASTR_ + ((((KB)*4+kg) ^ keyA)*8)])
#define MFMA8(v0,v1,v2,v3,a0_,a1_) do { \
        acc[0][0] = __builtin_amdgcn_mfma_f32_16x16x32_bf16(a0_, v0, acc[0][0],0,0,0); \
        acc[0][1] = __builtin_amdgcn_mfma_f32_16x16x32_bf16(a0_, v1, acc[0][1],0,0,0); \
        acc[0][2] = __builtin_amdgcn_mfma_f32_16x16x32_bf16(a0_, v2, acc[0][2],0,0,0); \
        acc[0][3] = __builtin_amdgcn_mfma_f32_16x16x32_bf16(a0_, v3, acc[0][3],0,0,0); \
        acc[1][0] = __builtin_amdgcn_mfma_f32_16x16x32_bf16(a1_, v0, acc[1][0],0,0,0); \
        acc[1][1] = __builtin_amdgcn_mfma_f32_16x16x32_bf16(a1_, v1, acc[1][1],0,0,0); \
        acc[1][2] = __builtin_amdgcn_mfma_f32_16x16x32_bf16(a1_, v2, acc[1][2],0,0,0); \
        acc[1][3] = __builtin_amdgcn_mfma_f32_16x16x32_bf16(a1_, v3, acc[1][3],0,0,0); \
    } while(0)

    bf16x8 a0,a1,a2,a3, d0,d1,d2,d3, e0,e1,e2,e3;
    LOADB(a0,a1,a2,a3, 0);
    LOADB(d0,d1,d2,d3, 1);
    LOADB(e0,e1,e2,e3, 2);
    for (int kb = 0; kb < 30; kb += 3) {
        bf16x8 af0, af1;
        af0 = LDSA0(kb);   af1 = LDSA1(kb);
        MFMA8(a0,a1,a2,a3, af0, af1);
        LOADB(a0,a1,a2,a3, kb+3);
        af0 = LDSA0(kb+1); af1 = LDSA1(kb+1);
        MFMA8(d0,d1,d2,d3, af0, af1);
        LOADB(d0,d1,d2,d3, kb+4);
        af0 = LDSA0(kb+2); af1 = LDSA1(kb+2);
        MFMA8(e0,e1,e2,e3, af0, af1);
        LOADB(e0,e1,e2,e3, kb+5);
    }
    {
        bf16x8 af0, af1;
        af0 = LDSA0(30); af1 = LDSA1(30);
        MFMA8(a0,a1,a2,a3, af0, af1);
        af0 = LDSA0(31); af1 = LDSA1(31);
        MFMA8(d0,d1,d2,d3, af0, af1);
        af0 = LDSA0(32); af1 = LDSA1(32);
        MFMA8(e0,e1,e2,e3, af0, af1);
    }
#undef LOADB
#undef LDSA0
#undef LDSA1
#undef MFMA8

    // ---- epilogue: gelu + *Wg2, reduce over this wave's 64 cols ----
    float rsum[2][4] = {{0.f,0.f,0.f,0.f},{0.f,0.f,0.f,0.f}};
    #pragma unroll
    for (int n = 0; n < 4; n++) {
        int colg = wv*64 + n*16 + lr;
        float bgv = bg1[colg], w2v = Wg2[colg];
        #pragma unroll
        for (int m = 0; m < 2; m++)
            #pragma unroll
            for (int r = 0; r < 4; r++) {
                float gv = gelu_f(acc[m][n][r] + bgv);
                rsum[m][r] = fmaf(gv, w2v, rsum[m][r]);
            }
    }
    #pragma unroll
    for (int off = 1; off < 16; off <<= 1)
        #pragma unroll
        for (int m = 0; m < 2; m++)
            #pragma unroll
            for (int r = 0; r < 4; r++)
                rsum[m][r] += __shfl_xor(rsum[m][r], off, 64);
    if (lr == 0) {
        #pragma unroll
        for (int m = 0; m < 2; m++)
            #pragma unroll
            for (int r = 0; r < 4; r++)
                red[wv][m*16 + kg*4 + r] = rsum[m][r];
    }
    __syncthreads();
    if (tid < RB5_)
        out[row0 + tid] = red[0][tid] + red[1][tid] + red[2][tid] + red[3][tid] + bg2[0];
}

// ---------------------------------------------------------------------------
extern "C" void kernel_launch(void* const* d_in, const int* in_sizes, int n_in,
                              void* d_out, int out_size, void* d_ws, size_t ws_size,
                              hipStream_t stream)
{
    const float* x    = (const float*)d_in[0];
    const float* t    = (const float*)d_in[1];
    const float* Wt1  = (const float*)d_in[2];
    const float* bt1  = (const float*)d_in[3];
    const float* Wt2  = (const float*)d_in[4];
    const float* bt2  = (const float*)d_in[5];
    const float* Wpf  = (const float*)d_in[6];
    const float* bpf  = (const float*)d_in[7];
    const float* Wpb  = (const float*)d_in[8];
    const float* bpb  = (const float*)d_in[9];
    const float* Wzf  = (const float*)d_in[10];
    const float* bzf  = (const float*)d_in[11];
    const float* Whf  = (const float*)d_in[12];
    const float* bhf  = (const float*)d_in[13];
    const float* Wzb  = (const float*)d_in[14];
    const float* bzb  = (const float*)d_in[15];
    const float* Whb  = (const float*)d_in[16];
    const float* bhb  = (const float*)d_in[17];
    const float* ln_g = (const float*)d_in[18];
    const float* ln_b = (const float*)d_in[19];
    const float* tsc  = (const float*)d_in[20];
    const float* Wg1  = (const float*)d_in[21];
    const float* bg1  = (const float*)d_in[22];
    const float* Wg2  = (const float*)d_in[23];
    const float* bg2  = (const float*)d_in[24];
    float* out = (float*)d_out;

    char* p = (char*)d_ws;
    auto carve = [&](size_t bytes) -> char* {
        char* q = p; p += (bytes + 255) & ~(size_t)255; return q;
    };

    unsigned short* WTf = (unsigned short*)carve((size_t)2*H_*H_*2);
    unsigned short* WTb = (unsigned short*)carve((size_t)2*H_*H_*2);
    uint4*          Pg  = (uint4*)carve((size_t)33*1024*16);

    const size_t perBatch = (size_t)L_*H_*2*2          // inpF + inpB
                          + (size_t)L_*NWS_*2*2        // ATF + ATB
                          + (size_t)L_*NT_*4           // tenc
                          + (size_t)CH_*H_*4*3*2;      // carries
    size_t fixedUsed = (size_t)(p - (char*)d_ws) + 64*1024;
    int NB = B_;
    while (NB > 1 && fixedUsed + (size_t)NB*perBatch > ws_size) NB >>= 1;

    unsigned short* inpF = (unsigned short*)carve((size_t)NB*L_*H_*2);
    unsigned short* inpB = (unsigned short*)carve((size_t)NB*L_*H_*2);
    unsigned short* ATF = (unsigned short*)carve((size_t)NB*L_*NWS_*2);
    unsigned short* ATB = (unsigned short*)carve((size_t)NB*L_*NWS_*2);
    float* tenc   = (float*)carve((size_t)NB*L_*NT_*4);
    float* Scar   = (float*)carve((size_t)2*NB*CH_*H_*4);
    float* Pcar   = (float*)carve((size_t)2*NB*CH_*H_*4);
    float* Hstart = (float*)carve((size_t)2*NB*CH_*H_*4);

    {
        dim3 g(H_/32, H_/32);
        kT<<<g, 256, 0, stream>>>(Wzf, WTf,         H_, H_, H_);
        kT<<<g, 256, 0, stream>>>(Whf, WTf + H_*H_, H_, H_, H_);
        kT<<<g, 256, 0, stream>>>(Wzb, WTb,         H_, H_, H_);
        kT<<<g, 256, 0, stream>>>(Whb, WTb + H_*H_, H_, H_, H_);
        kP<<<132, 256, 0, stream>>>(Wg1, Pg);
    }

    for (int b0 = 0; b0 < B_; b0 += NB) {
        int rows = NB * L_;
        int halfTiles = (rows/128) * 8;
        int nwg3 = 2 * halfTiles;

        k1_tenc_inp<<<rows/4, 256, 0, stream>>>(
            x + (size_t)b0*L_*2, t + (size_t)b0*L_,
            Wt1, bt1, Wt2, bt2, Wpf, bpf, Wpb, bpb,
            tenc, inpF, inpB);

        k3g<<<nwg3, 256, 0, stream>>>(inpF, inpB, WTf, WTb, ATF, ATB,
                                      nwg3, halfTiles);

        int scanThreads = 2*NB*H_*CH_;
        k4a<<<scanThreads/256, 256, 0, stream>>>(ATF, ATB, bzf, bhf, bzb, bhb,
                                                 Scar, Pcar, NB);
        k4b<<<(2*NB*H_)/256, 256, 0, stream>>>(Scar, Pcar, Hstart, NB);

        k5_fused<<<rows/RB5_, 256, 0, stream>>>(
            ATF, ATB, Hstart, tenc, ln_g, ln_b, tsc,
            Pg, bg1, Wg2, bg2, out + (size_t)b0*L_, NB);
    }
}

// Round 18
// 270.592 us; speedup vs baseline: 1.1487x; 1.0681x over previous
//
#include <hip/hip_runtime.h>
#include <hip/hip_bf16.h>
#include <math.h>

#define B_    16
#define L_    2048
#define H_    512
#define NT_   8
#define OUT_  1032
#define HEAD_ 256
#define CH_   16
#define CL_   (L_/CH_)   // 128
#define NWS_  1152       // AT row stride in shorts (z|h -> S|PP in place)

// k5 A-LDS geometry: 32 rows, 136 chunks of 16B (2176B row), XOR-swizzled
#define ACH_  136
#define ASTR_ (ACH_*8)   // shorts per row = 1088
#define RB5_  32         // rows per k5 block

typedef short bf16x8 __attribute__((ext_vector_type(8)));
typedef float f32x4  __attribute__((ext_vector_type(4)));

__device__ __forceinline__ float b2f(unsigned short u) {
    union { unsigned int u32; float f; } v; v.u32 = ((unsigned int)u) << 16; return v.f;
}
__device__ __forceinline__ unsigned short f2b(float f) {
    __hip_bfloat16 h = __float2bfloat16(f);
    return *reinterpret_cast<unsigned short*>(&h);
}
__device__ __forceinline__ float sigmoid_f(float x) {
    return 1.f / (1.f + exp2f(-1.44269504f * x));
}
__device__ __forceinline__ float tanh_f(float x) {
    float e = exp2f(2.88539008f * x);
    return 1.f - 2.f / (e + 1.f);
}
__device__ __forceinline__ float gelu_f(float g) {
    float u  = 0.70710678118654752f * g;
    float ax = fabsf(u);
    float t  = 1.f / (1.f + 0.3275911f * ax);
    float poly = ((((1.061405429f*t - 1.453152027f)*t + 1.421413741f)*t
                   - 0.284496736f)*t + 0.254829592f)*t;
    float e  = exp2f(-1.44269504f * ax * ax);
    float er = 1.f - poly * e;
    er = (u < 0.f) ? -er : er;
    return 0.5f * g * (1.f + er);
}

// ---------------------------------------------------------------------------
// kT: transpose + f32->bf16. in f32 [R][C] -> out bf16 [C][RP], zero r>=R.
// ---------------------------------------------------------------------------
__global__ __launch_bounds__(256) void kT(const float* __restrict__ in,
                                          unsigned short* __restrict__ out,
                                          int R, int C, int RP)
{
    __shared__ float tile[32][33];
    int c0 = blockIdx.x * 32, r0 = blockIdx.y * 32;
    int tx = threadIdx.x & 31, ty = threadIdx.x >> 5;
    #pragma unroll
    for (int j = 0; j < 32; j += 8) {
        int r = r0 + ty + j, c = c0 + tx;
        tile[ty + j][tx] = (r < R && c < C) ? in[(size_t)r*C + c] : 0.f;
    }
    __syncthreads();
    #pragma unroll
    for (int j = 0; j < 32; j += 8) {
        int c = c0 + ty + j, r = r0 + tx;
        if (c < C && r < RP) out[(size_t)c*RP + r] = f2b(tile[tx][ty + j]);
    }
}

// ---------------------------------------------------------------------------
// kP: pack Wg1 (f32 [OUT_][256]) into MFMA B-fragment chunks, 33 K-blocks.
// ---------------------------------------------------------------------------
__global__ __launch_bounds__(256) void kP(const float* __restrict__ Wg1,
                                          uint4* __restrict__ P)
{
    int idx = blockIdx.x*256 + threadIdx.x;
    if (idx >= 33*1024) return;
    int kb = idx >> 10;
    int rem = idx & 1023;
    int c  = rem >> 2;
    int kg = rem & 3;
    int k0 = kb*32 + kg*8;
    unsigned short o[8];
    #pragma unroll
    for (int j = 0; j < 8; j++) {
        int k = k0 + j;
        o[j] = (k < OUT_) ? f2b(Wg1[(size_t)k*HEAD_ + c]) : (unsigned short)0;
    }
    P[idx] = *(const uint4*)o;
}

// ---------------------------------------------------------------------------
// K1 (both dirs): t_enc MLP + inp_{f,b} = xc @ Wp{f,b} + bp{f,b}. wave-per-row.
// ---------------------------------------------------------------------------
__global__ __launch_bounds__(256) void k1_tenc_inp(
    const float* __restrict__ x, const float* __restrict__ t,
    const float* __restrict__ Wt1, const float* __restrict__ bt1,
    const float* __restrict__ Wt2, const float* __restrict__ bt2,
    const float* __restrict__ Wpf, const float* __restrict__ bpf,
    const float* __restrict__ Wpb, const float* __restrict__ bpb,
    float* __restrict__ t_enc,
    unsigned short* __restrict__ inp_f, unsigned short* __restrict__ inp_b)
{
    int wv = threadIdx.x >> 6, lane = threadIdx.x & 63;
    size_t row = (size_t)blockIdx.x*4 + wv;
    float tv = t[row];
    float r1[NT_], te[NT_];
    #pragma unroll
    for (int k = 0; k < NT_; k++) r1[k] = fmaxf(tv*Wt1[k] + bt1[k], 0.f);
    #pragma unroll
    for (int j = 0; j < NT_; j++) {
        float a = bt2[j];
        #pragma unroll
        for (int k = 0; k < NT_; k++) a = fmaf(r1[k], Wt2[k*NT_+j], a);
        te[j] = a;
    }
    if (lane < NT_) t_enc[row*NT_ + lane] = te[lane];
    float x0 = x[row*2+0], x1 = x[row*2+1];
    int c0 = lane*8;
    float af[8], ab[8];
    #pragma unroll
    for (int j = 0; j < 8; j++) {
        int c = c0 + j;
        af[j] = fmaf(x0, Wpf[c], fmaf(x1, Wpf[H_+c], bpf[c]));
        ab[j] = fmaf(x0, Wpb[c], fmaf(x1, Wpb[H_+c], bpb[c]));
    }
    #pragma unroll
    for (int k = 0; k < NT_; k++) {
        #pragma unroll
        for (int j = 0; j < 8; j++) {
            af[j] = fmaf(te[k], Wpf[(2+k)*H_+c0+j], af[j]);
            ab[j] = fmaf(te[k], Wpb[(2+k)*H_+c0+j], ab[j]);
        }
    }
    unsigned short of[8], ob[8];
    #pragma unroll
    for (int j = 0; j < 8; j++) { of[j] = f2b(af[j]); ob[j] = f2b(ab[j]); }
    *(uint4*)&inp_f[row*H_ + c0] = *(const uint4*)of;
    *(uint4*)&inp_b[row*H_ + c0] = *(const uint4*)ob;
}

// ---------------------------------------------------------------------------
// K3g (both dirs): AT{F,B}[row][0..1023] = inp{f,b} @ [Wz|Wh].
// Round-15 body + 2-deep register prefetch (named p/q buffer sets, each load
// issued one full iteration before use) + __launch_bounds__(256,3) so the
// allocator keeps the pipeline live (k5 round-15 lesson). Scalar epilogue
// stores (best-measured variant). XCD remap.
// ---------------------------------------------------------------------------
__global__ __launch_bounds__(256, 3) void k3g(
    const unsigned short* __restrict__ inpF,
    const unsigned short* __restrict__ inpB,
    const unsigned short* __restrict__ WTf,   // [1024][512] (Wz rows, Wh rows)
    const unsigned short* __restrict__ WTb,
    unsigned short* __restrict__ ATF,
    unsigned short* __restrict__ ATB,
    int nwg, int halfTiles)
{
    __shared__ __align__(16) unsigned short As[128*40];
    __shared__ __align__(16) unsigned short Bs[128*40];
    int tid = threadIdx.x;
    int lane = tid & 63, w = tid >> 6;
    int wm = w >> 1, wn = w & 1;
    int kg = lane >> 4, lr = lane & 15;

    int bid = blockIdx.x;
    int cpx = nwg >> 3;
    int tile = (bid & 7) * cpx + (bid >> 3);
    int dir  = tile >= halfTiles;
    int lt   = dir ? (tile - halfTiles) : tile;
    int row0 = (lt >> 3) * 128;
    int n0   = (lt & 7) * 128;
    const unsigned short* inp = dir ? inpB : inpF;
    const unsigned short* WT  = dir ? WTb : WTf;
    unsigned short* zt_out    = dir ? ATB : ATF;

    f32x4 acc[4][4];
    #pragma unroll
    for (int m = 0; m < 4; m++)
        #pragma unroll
        for (int n = 0; n < 4; n++) acc[m][n] = (f32x4){0.f,0.f,0.f,0.f};

    int ar = tid >> 1, aseg = tid & 1;
    const uint4* gaBase = (const uint4*)&inp[(size_t)(row0+ar)*H_ + aseg*16];
    const uint4* gbBase = (const uint4*)&WT [(size_t)(n0  +ar)*H_ + aseg*16];
    // k0 shorts -> k0/8 uint4 from base

    uint4 pA0 = gaBase[0], pA1 = gaBase[1];
    uint4 pB0 = gbBase[0], pB1 = gbBase[1];
    uint4 qA0 = gaBase[4], qA1 = gaBase[5];   // k=32
    uint4 qB0 = gbBase[4], qB1 = gbBase[5];

#define K3STEP(RA0,RA1,RB0,RB1, NEXTK) do { \
        __syncthreads(); \
        *(uint4*)&As[ar*40 + aseg*16]     = RA0; \
        *(uint4*)&As[ar*40 + aseg*16 + 8] = RA1; \
        *(uint4*)&Bs[ar*40 + aseg*16]     = RB0; \
        *(uint4*)&Bs[ar*40 + aseg*16 + 8] = RB1; \
        __syncthreads(); \
        if ((NEXTK) < H_) { \
            RA0 = gaBase[(NEXTK)>>3]; RA1 = gaBase[((NEXTK)>>3) + 1]; \
            RB0 = gbBase[(NEXTK)>>3]; RB1 = gbBase[((NEXTK)>>3) + 1]; \
        } \
        bf16x8 af[4], bf[4]; \
        _Pragma("unroll") \
        for (int m = 0; m < 4; m++) \
            af[m] = *(const bf16x8*)&As[(wm*64 + m*16 + lr)*40 + kg*8]; \
        _Pragma("unroll") \
        for (int n = 0; n < 4; n++) \
            bf[n] = *(const bf16x8*)&Bs[(wn*64 + n*16 + lr)*40 + kg*8]; \
        _Pragma("unroll") \
        for (int m = 0; m < 4; m++) \
            _Pragma("unroll") \
            for (int n = 0; n < 4; n++) \
                acc[m][n] = __builtin_amdgcn_mfma_f32_16x16x32_bf16(af[m], bf[n], acc[m][n], 0, 0, 0); \
    } while(0)

    for (int k0 = 0; k0 < H_; k0 += 64) {
        K3STEP(pA0,pA1,pB0,pB1, k0+64);
        K3STEP(qA0,qA1,qB0,qB1, k0+96);
    }
#undef K3STEP

    #pragma unroll
    for (int m = 0; m < 4; m++)
        #pragma unroll
        for (int n = 0; n < 4; n++) {
            int colg = n0 + wn*64 + n*16 + lr;
            #pragma unroll
            for (int r = 0; r < 4; r++) {
                int rowg = row0 + wm*64 + m*16 + kg*4 + r;
                zt_out[(size_t)rowg*NWS_ + colg] = f2b(acc[m][n][r]);
            }
        }
}

// ---------------------------------------------------------------------------
// K4a: bias + activations + chunked scan pass A, in place on AT rows.
// ---------------------------------------------------------------------------
__global__ __launch_bounds__(256) void k4a(
    unsigned short* __restrict__ ATF, unsigned short* __restrict__ ATB,
    const float* __restrict__ bzf, const float* __restrict__ bhf,
    const float* __restrict__ bzb, const float* __restrict__ bhb,
    float* __restrict__ Scar, float* __restrict__ Pcar, int nb)
{
    int g = blockIdx.x*256 + threadIdx.x;
    int col   = g & (H_-1);
    int chunk = (g >> 9) & (CH_-1);
    int rest  = g >> 13;
    int bb    = rest % nb;
    int dir   = rest / nb;
    unsigned short* AT = dir ? ATB : ATF;
    float bzv = (dir ? bzb : bzf)[col];
    float bhv = (dir ? bhb : bhf)[col];
    size_t base = (size_t)bb * L_ * NWS_ + col;
    float h = 0.f, pp = 1.f;
    if (dir == 0) {
        int lo = chunk * CL_;
        for (int p = 0; p < CL_; p += 8) {
            unsigned short zv[8], hv[8];
            #pragma unroll
            for (int j = 0; j < 8; j++) {
                size_t idx = base + (size_t)(lo+p+j)*NWS_;
                zv[j] = AT[idx]; hv[j] = AT[idx + H_];
            }
            #pragma unroll
            for (int j = 0; j < 8; j++) {
                size_t idx = base + (size_t)(lo+p+j)*NWS_;
                float zg = sigmoid_f(b2f(zv[j]) + bzv);
                float a  = 1.f - zg;
                float bg = zg * tanh_f(b2f(hv[j]) + bhv);
                AT[idx]      = f2b(h);
                AT[idx + H_] = f2b(pp);
                h = fmaf(a, h, bg);
                pp *= a;
            }
        }
    } else {
        int hi = chunk * CL_ + CL_ - 1;
        for (int p = 0; p < CL_; p += 8) {
            unsigned short zv[8], hv[8];
            #pragma unroll
            for (int j = 0; j < 8; j++) {
                size_t idx = base + (size_t)(hi-p-j)*NWS_;
                zv[j] = AT[idx]; hv[j] = AT[idx + H_];
            }
            #pragma unroll
            for (int j = 0; j < 8; j++) {
                size_t idx = base + (size_t)(hi-p-j)*NWS_;
                float zg = sigmoid_f(b2f(zv[j]) + bzv);
                float a  = 1.f - zg;
                float bg = zg * tanh_f(b2f(hv[j]) + bhv);
                AT[idx]      = f2b(h);
                AT[idx + H_] = f2b(pp);
                h = fmaf(a, h, bg);
                pp *= a;
            }
        }
    }
    int ci = ((dir*nb + bb)*CH_ + chunk)*H_ + col;
    Scar[ci] = h; Pcar[ci] = pp;
}

// K4b: chain carries across chunks.
__global__ __launch_bounds__(256) void k4b(
    const float* __restrict__ Scar, const float* __restrict__ Pcar,
    float* __restrict__ Hstart, int nb)
{
    int g = blockIdx.x*256 + threadIdx.x;
    int col  = g & (H_-1);
    int rest = g >> 9;
    int bb   = rest % nb;
    int dir  = rest / nb;
    int baseci = (dir*nb + bb)*CH_;
    float h = 0.f;
    if (dir == 0) {
        for (int c = 0; c < CH_; c++) {
            int ci = (baseci + c)*H_ + col;
            Hstart[ci] = h;
            h = Scar[ci] + Pcar[ci]*h;
        }
    } else {
        for (int c = CH_-1; c >= 0; c--) {
            int ci = (baseci + c)*H_ + col;
            Hstart[ci] = h;
            h = Scar[ci] + Pcar[ci]*h;
        }
    }
}

// ---------------------------------------------------------------------------
// K5 fused: LN (rolling-1 prefetch) -> XOR-swizzled LDS A, barrier-free head
// GEMM (3-deep B register pipeline), gelu*Wg2 + shfl row-reduce.
// __launch_bounds__(256,2): keep pipelines live in registers (round-15 win).
// ---------------------------------------------------------------------------
__global__ __launch_bounds__(256, 2) void k5_fused(
    const unsigned short* __restrict__ ATF, const unsigned short* __restrict__ ATB,
    const float* __restrict__ Hstart,
    const float* __restrict__ tenc,
    const float* __restrict__ ln_g, const float* __restrict__ ln_b,
    const float* __restrict__ tsp,
    const uint4* __restrict__ P,              // [33*1024] packed Wg1 fragments
    const float* __restrict__ bg1, const float* __restrict__ Wg2,
    const float* __restrict__ bg2,
    float* __restrict__ out, int nb)
{
    __shared__ __align__(16) unsigned short A[RB5_*ASTR_];   // 68 KB
    __shared__ float red[4][RB5_];
    int tid = threadIdx.x, lane = tid & 63, wv = tid >> 6;
    int kg = lane >> 4, lr = lane & 15;
    int row0 = blockIdx.x * RB5_;
    float ts = tsp[0];

    int bb    = row0 >> 11;          // / L_
    int chunk = (row0 & (L_-1)) >> 7;
    int cif = (bb*CH_ + chunk)*H_;
    int cib = ((nb + bb)*CH_ + chunk)*H_;
    int c0 = lane*8;
    float4 hfa = *(const float4*)&Hstart[cif + c0];
    float4 hfb = *(const float4*)&Hstart[cif + c0 + 4];
    float4 hba = *(const float4*)&Hstart[cib + c0];
    float4 hbb = *(const float4*)&Hstart[cib + c0 + 4];
    float h0f[8] = {hfa.x,hfa.y,hfa.z,hfa.w,hfb.x,hfb.y,hfb.z,hfb.w};
    float h0b[8] = {hba.x,hba.y,hba.z,hba.w,hbb.x,hbb.y,hbb.z,hbb.w};

    float gf[8], bf_[8], gb_[8], bb_[8];
    #pragma unroll
    for (int j = 0; j < 8; j++) {
        gf[j]  = ln_g[c0+j];     bf_[j] = ln_b[c0+j];
        gb_[j] = ln_g[H_+c0+j];  bb_[j] = ln_b[H_+c0+j];
    }
    float gt = 0.f, bt = 0.f;
    if (lane < NT_) { gt = ln_g[2*H_+lane]; bt = ln_b[2*H_+lane]; }

    // ---- LN phase with rolling-1 row prefetch ----
    size_t rowBase = (size_t)(row0 + wv*8) * NWS_;
    uint4 cSF = *(const uint4*)&ATF[rowBase + c0];
    uint4 cPF = *(const uint4*)&ATF[rowBase + H_ + c0];
    uint4 cSB = *(const uint4*)&ATB[rowBase + c0];
    uint4 cPB = *(const uint4*)&ATB[rowBase + H_ + c0];

    #pragma unroll
    for (int i = 0; i < 8; i++) {
        int r = wv*8 + i;
        size_t row = (size_t)row0 + r;
        uint4 SF = cSF, PF = cPF, SB = cSB, PB = cPB;
        if (i < 7) {
            size_t rb2 = rowBase + (size_t)(i+1)*NWS_;
            cSF = *(const uint4*)&ATF[rb2 + c0];
            cPF = *(const uint4*)&ATF[rb2 + H_ + c0];
            cSB = *(const uint4*)&ATB[rb2 + c0];
            cPB = *(const uint4*)&ATB[rb2 + H_ + c0];
        }
        const unsigned short* sf = (const unsigned short*)&SF;
        const unsigned short* pf = (const unsigned short*)&PF;
        const unsigned short* sb = (const unsigned short*)&SB;
        const unsigned short* pb = (const unsigned short*)&PB;
        float fv[8], bv[8];
        float S = 0.f, Q = 0.f;
        #pragma unroll
        for (int j = 0; j < 8; j++) {
            fv[j] = fmaf(b2f(pf[j]), h0f[j], b2f(sf[j]));
            S += fv[j]; Q += fv[j]*fv[j];
            bv[j] = fmaf(b2f(pb[j]), h0b[j], b2f(sb[j]));
            S += bv[j]; Q += bv[j]*bv[j];
        }
        float tv = 0.f;
        if (lane < NT_) { tv = tenc[row*NT_ + lane]; S += tv; Q += tv*tv; }
        #pragma unroll
        for (int off = 32; off > 0; off >>= 1) {
            S += __shfl_xor(S, off, 64);
            Q += __shfl_xor(Q, off, 64);
        }
        float mu = S * (1.f/1032.f);
        float rs = rsqrtf(Q * (1.f/1032.f) - mu*mu + 1e-5f);
        int key = r & 7;
        unsigned short o[8];
        #pragma unroll
        for (int j = 0; j < 8; j++) o[j] = f2b((fv[j]-mu)*rs*gf[j] + bf_[j]);
        *(uint4*)&A[r*ASTR_ + ((lane ^ key)*8)] = *(const uint4*)o;
        #pragma unroll
        for (int j = 0; j < 8; j++) o[j] = f2b((bv[j]-mu)*rs*gb_[j] + bb_[j]);
        *(uint4*)&A[r*ASTR_ + (((64+lane) ^ key)*8)] = *(const uint4*)o;
        if (lane < NT_) {
            A[r*ASTR_ + ((128 ^ key)*8) + lane] =
                f2b(((tv-mu)*rs*gt + bt) * ts);
        } else {
            int cc = 128 + (lane >> 3);
            A[r*ASTR_ + ((cc ^ key)*8) + (lane & 7)] = 0;
        }
    }
    __syncthreads();

    // ---- GEMM phase (no barriers, 3-deep B pipeline) ----
    f32x4 acc[2][4];
    #pragma unroll
    for (int m = 0; m < 2; m++)
        #pragma unroll
        for (int n = 0; n < 4; n++) acc[m][n] = (f32x4){0.f,0.f,0.f,0.f};

    const uint4* Pw = P + wv*256 + lr*4 + kg;
    int keyA = lr & 7;

#define LOADB(v0,v1,v2,v3,KB) do { \
        const uint4* q_ = Pw + (KB)*1024; \
        v0 = *(const bf16x8*)&q_[0]; \
        v1 = *(const bf16x8*)&q_[64]; \
        v2 = *(const bf16x8*)&q_[128]; \
        v3 = *(const bf16x8*)&q_[192]; \
    } while(0)
#define LDSA0(KB) (*(const bf16x8*)&A[lr*ASTR_      + ((((KB)*4+kg) ^ keyA)*8)])
#define LDSA1(KB) (*(const bf16x8*)&A[(16+lr)*ASTR_ + ((((KB)*4+kg) ^ keyA)*8)])
#define MFMA8(v0,v1,v2,v3,a0_,a1_) do { \
        acc[0][0] = __builtin_amdgcn_mfma_f32_16x16x32_bf16(a0_, v0, acc[0][0],0,0,0); \
        acc[0][1] = __builtin_amdgcn_mfma_f32_16x16x32_bf16(a0_, v1, acc[0][1],0,0,0); \
        acc[0][2] = __builtin_amdgcn_mfma_f32_16x16x32_bf16(a0_, v2, acc[0][2],0,0,0); \
        acc[0][3] = __builtin_amdgcn_mfma_f32_16x16x32_bf16(a0_, v3, acc[0][3],0,0,0); \
        acc[1][0] = __builtin_amdgcn_mfma_f32_16x16x32_bf16(a1_, v0, acc[1][0],0,0,0); \
        acc[1][1] = __builtin_amdgcn_mfma_f32_16x16x32_bf16(a1_, v1, acc[1][1],0,0,0); \
        acc[1][2] = __builtin_amdgcn_mfma_f32_16x16x32_bf16(a1_, v2, acc[1][2],0,0,0); \
        acc[1][3] = __builtin_amdgcn_mfma_f32_16x16x32_bf16(a1_, v3, acc[1][3],0,0,0); \
    } while(0)

    bf16x8 a0,a1,a2,a3, d0,d1,d2,d3, e0,e1,e2,e3;
    LOADB(a0,a1,a2,a3, 0);
    LOADB(d0,d1,d2,d3, 1);
    LOADB(e0,e1,e2,e3, 2);
    for (int kb = 0; kb < 30; kb += 3) {
        bf16x8 af0, af1;
        af0 = LDSA0(kb);   af1 = LDSA1(kb);
        MFMA8(a0,a1,a2,a3, af0, af1);
        LOADB(a0,a1,a2,a3, kb+3);
        af0 = LDSA0(kb+1); af1 = LDSA1(kb+1);
        MFMA8(d0,d1,d2,d3, af0, af1);
        LOADB(d0,d1,d2,d3, kb+4);
        af0 = LDSA0(kb+2); af1 = LDSA1(kb+2);
        MFMA8(e0,e1,e2,e3, af0, af1);
        LOADB(e0,e1,e2,e3, kb+5);
    }
    {
        bf16x8 af0, af1;
        af0 = LDSA0(30); af1 = LDSA1(30);
        MFMA8(a0,a1,a2,a3, af0, af1);
        af0 = LDSA0(31); af1 = LDSA1(31);
        MFMA8(d0,d1,d2,d3, af0, af1);
        af0 = LDSA0(32); af1 = LDSA1(32);
        MFMA8(e0,e1,e2,e3, af0, af1);
    }
#undef LOADB
#undef LDSA0
#undef LDSA1
#undef MFMA8

    // ---- epilogue: gelu + *Wg2, reduce over this wave's 64 cols ----
    float rsum[2][4] = {{0.f,0.f,0.f,0.f},{0.f,0.f,0.f,0.f}};
    #pragma unroll
    for (int n = 0; n < 4; n++) {
        int colg = wv*64 + n*16 + lr;
        float bgv = bg1[colg], w2v = Wg2[colg];
        #pragma unroll
        for (int m = 0; m < 2; m++)
            #pragma unroll
            for (int r = 0; r < 4; r++) {
                float gv = gelu_f(acc[m][n][r] + bgv);
                rsum[m][r] = fmaf(gv, w2v, rsum[m][r]);
            }
    }
    #pragma unroll
    for (int off = 1; off < 16; off <<= 1)
        #pragma unroll
        for (int m = 0; m < 2; m++)
            #pragma unroll
            for (int r = 0; r < 4; r++)
                rsum[m][r] += __shfl_xor(rsum[m][r], off, 64);
    if (lr == 0) {
        #pragma unroll
        for (int m = 0; m < 2; m++)
            #pragma unroll
            for (int r = 0; r < 4; r++)
                red[wv][m*16 + kg*4 + r] = rsum[m][r];
    }
    __syncthreads();
    if (tid < RB5_)
        out[row0 + tid] = red[0][tid] + red[1][tid] + red[2][tid] + red[3][tid] + bg2[0];
}

// ---------------------------------------------------------------------------
extern "C" void kernel_launch(void* const* d_in, const int* in_sizes, int n_in,
                              void* d_out, int out_size, void* d_ws, size_t ws_size,
                              hipStream_t stream)
{
    const float* x    = (const float*)d_in[0];
    const float* t    = (const float*)d_in[1];
    const float* Wt1  = (const float*)d_in[2];
    const float* bt1  = (const float*)d_in[3];
    const float* Wt2  = (const float*)d_in[4];
    const float* bt2  = (const float*)d_in[5];
    const float* Wpf  = (const float*)d_in[6];
    const float* bpf  = (const float*)d_in[7];
    const float* Wpb  = (const float*)d_in[8];
    const float* bpb  = (const float*)d_in[9];
    const float* Wzf  = (const float*)d_in[10];
    const float* bzf  = (const float*)d_in[11];
    const float* Whf  = (const float*)d_in[12];
    const float* bhf  = (const float*)d_in[13];
    const float* Wzb  = (const float*)d_in[14];
    const float* bzb  = (const float*)d_in[15];
    const float* Whb  = (const float*)d_in[16];
    const float* bhb  = (const float*)d_in[17];
    const float* ln_g = (const float*)d_in[18];
    const float* ln_b = (const float*)d_in[19];
    const float* tsc  = (const float*)d_in[20];
    const float* Wg1  = (const float*)d_in[21];
    const float* bg1  = (const float*)d_in[22];
    const float* Wg2  = (const float*)d_in[23];
    const float* bg2  = (const float*)d_in[24];
    float* out = (float*)d_out;

    char* p = (char*)d_ws;
    auto carve = [&](size_t bytes) -> char* {
        char* q = p; p += (bytes + 255) & ~(size_t)255; return q;
    };

    unsigned short* WTf = (unsigned short*)carve((size_t)2*H_*H_*2);
    unsigned short* WTb = (unsigned short*)carve((size_t)2*H_*H_*2);
    uint4*          Pg  = (uint4*)carve((size_t)33*1024*16);

    const size_t perBatch = (size_t)L_*H_*2*2          // inpF + inpB
                          + (size_t)L_*NWS_*2*2        // ATF + ATB
                          + (size_t)L_*NT_*4           // tenc
                          + (size_t)CH_*H_*4*3*2;      // carries
    size_t fixedUsed = (size_t)(p - (char*)d_ws) + 64*1024;
    int NB = B_;
    while (NB > 1 && fixedUsed + (size_t)NB*perBatch > ws_size) NB >>= 1;

    unsigned short* inpF = (unsigned short*)carve((size_t)NB*L_*H_*2);
    unsigned short* inpB = (unsigned short*)carve((size_t)NB*L_*H_*2);
    unsigned short* ATF = (unsigned short*)carve((size_t)NB*L_*NWS_*2);
    unsigned short* ATB = (unsigned short*)carve((size_t)NB*L_*NWS_*2);
    float* tenc   = (float*)carve((size_t)NB*L_*NT_*4);
    float* Scar   = (float*)carve((size_t)2*NB*CH_*H_*4);
    float* Pcar   = (float*)carve((size_t)2*NB*CH_*H_*4);
    float* Hstart = (float*)carve((size_t)2*NB*CH_*H_*4);

    {
        dim3 g(H_/32, H_/32);
        kT<<<g, 256, 0, stream>>>(Wzf, WTf,         H_, H_, H_);
        kT<<<g, 256, 0, stream>>>(Whf, WTf + H_*H_, H_, H_, H_);
        kT<<<g, 256, 0, stream>>>(Wzb, WTb,         H_, H_, H_);
        kT<<<g, 256, 0, stream>>>(Whb, WTb + H_*H_, H_, H_, H_);
        kP<<<132, 256, 0, stream>>>(Wg1, Pg);
    }

    for (int b0 = 0; b0 < B_; b0 += NB) {
        int rows = NB * L_;
        int halfTiles = (rows/128) * 8;
        int nwg3 = 2 * halfTiles;

        k1_tenc_inp<<<rows/4, 256, 0, stream>>>(
            x + (size_t)b0*L_*2, t + (size_t)b0*L_,
            Wt1, bt1, Wt2, bt2, Wpf, bpf, Wpb, bpb,
            tenc, inpF, inpB);

        k3g<<<nwg3, 256, 0, stream>>>(inpF, inpB, WTf, WTb, ATF, ATB,
                                      nwg3, halfTiles);

        int scanThreads = 2*NB*H_*CH_;
        k4a<<<scanThreads/256, 256, 0, stream>>>(ATF, ATB, bzf, bhf, bzb, bhb,
                                                 Scar, Pcar, NB);
        k4b<<<(2*NB*H_)/256, 256, 0, stream>>>(Scar, Pcar, Hstart, NB);

        k5_fused<<<rows/RB5_, 256, 0, stream>>>(
            ATF, ATB, Hstart, tenc, ln_g, ln_b, tsc,
            Pg, bg1, Wg2, bg2, out + (size_t)b0*L_, NB);
    }
}

// Round 19
// 266.831 us; speedup vs baseline: 1.1649x; 1.0141x over previous
//
#include <hip/hip_runtime.h>
#include <hip/hip_bf16.h>
#include <math.h>

#define B_    16
#define L_    2048
#define H_    512
#define NT_   8
#define OUT_  1032
#define HEAD_ 256
#define CH_   16
#define CL_   (L_/CH_)   // 128
#define NWS_  1152       // AT row stride in shorts (z|h -> S|PP in place)

// k5 A-LDS geometry: 32 rows, 136 chunks of 16B (2176B row), XOR-swizzled
#define ACH_  136
#define ASTR_ (ACH_*8)   // shorts per row = 1088
#define RB5_  32         // rows per k5 block

typedef short bf16x8 __attribute__((ext_vector_type(8)));
typedef float f32x4  __attribute__((ext_vector_type(4)));

__device__ __forceinline__ float b2f(unsigned short u) {
    union { unsigned int u32; float f; } v; v.u32 = ((unsigned int)u) << 16; return v.f;
}
__device__ __forceinline__ unsigned short f2b(float f) {
    __hip_bfloat16 h = __float2bfloat16(f);
    return *reinterpret_cast<unsigned short*>(&h);
}
__device__ __forceinline__ float sigmoid_f(float x) {
    return 1.f / (1.f + exp2f(-1.44269504f * x));
}
__device__ __forceinline__ float tanh_f(float x) {
    float e = exp2f(2.88539008f * x);
    return 1.f - 2.f / (e + 1.f);
}
__device__ __forceinline__ float gelu_f(float g) {
    float u  = 0.70710678118654752f * g;
    float ax = fabsf(u);
    float t  = 1.f / (1.f + 0.3275911f * ax);
    float poly = ((((1.061405429f*t - 1.453152027f)*t + 1.421413741f)*t
                   - 0.284496736f)*t + 0.254829592f)*t;
    float e  = exp2f(-1.44269504f * ax * ax);
    float er = 1.f - poly * e;
    er = (u < 0.f) ? -er : er;
    return 0.5f * g * (1.f + er);
}

// async global->LDS, 16B per lane; LDS dest is wave-uniform base + lane*16
__device__ __forceinline__ void gld16(unsigned short* lds, const unsigned short* g) {
    __builtin_amdgcn_global_load_lds(
        (const __attribute__((address_space(1))) unsigned int*)(const void*)g,
        (__attribute__((address_space(3))) unsigned int*)(void*)lds,
        16, 0, 0);
}

// ---------------------------------------------------------------------------
// kT: transpose + f32->bf16. in f32 [R][C] -> out bf16 [C][RP], zero r>=R.
// ---------------------------------------------------------------------------
__global__ __launch_bounds__(256) void kT(const float* __restrict__ in,
                                          unsigned short* __restrict__ out,
                                          int R, int C, int RP)
{
    __shared__ float tile[32][33];
    int c0 = blockIdx.x * 32, r0 = blockIdx.y * 32;
    int tx = threadIdx.x & 31, ty = threadIdx.x >> 5;
    #pragma unroll
    for (int j = 0; j < 32; j += 8) {
        int r = r0 + ty + j, c = c0 + tx;
        tile[ty + j][tx] = (r < R && c < C) ? in[(size_t)r*C + c] : 0.f;
    }
    __syncthreads();
    #pragma unroll
    for (int j = 0; j < 32; j += 8) {
        int c = c0 + ty + j, r = r0 + tx;
        if (c < C && r < RP) out[(size_t)c*RP + r] = f2b(tile[tx][ty + j]);
    }
}

// ---------------------------------------------------------------------------
// kP: pack Wg1 (f32 [OUT_][256]) into MFMA B-fragment chunks, 33 K-blocks.
// ---------------------------------------------------------------------------
__global__ __launch_bounds__(256) void kP(const float* __restrict__ Wg1,
                                          uint4* __restrict__ P)
{
    int idx = blockIdx.x*256 + threadIdx.x;
    if (idx >= 33*1024) return;
    int kb = idx >> 10;
    int rem = idx & 1023;
    int c  = rem >> 2;
    int kg = rem & 3;
    int k0 = kb*32 + kg*8;
    unsigned short o[8];
    #pragma unroll
    for (int j = 0; j < 8; j++) {
        int k = k0 + j;
        o[j] = (k < OUT_) ? f2b(Wg1[(size_t)k*HEAD_ + c]) : (unsigned short)0;
    }
    P[idx] = *(const uint4*)o;
}

// ---------------------------------------------------------------------------
// K1 (both dirs): t_enc MLP + inp_{f,b} = xc @ Wp{f,b} + bp{f,b}. wave-per-row.
// ---------------------------------------------------------------------------
__global__ __launch_bounds__(256) void k1_tenc_inp(
    const float* __restrict__ x, const float* __restrict__ t,
    const float* __restrict__ Wt1, const float* __restrict__ bt1,
    const float* __restrict__ Wt2, const float* __restrict__ bt2,
    const float* __restrict__ Wpf, const float* __restrict__ bpf,
    const float* __restrict__ Wpb, const float* __restrict__ bpb,
    float* __restrict__ t_enc,
    unsigned short* __restrict__ inp_f, unsigned short* __restrict__ inp_b)
{
    int wv = threadIdx.x >> 6, lane = threadIdx.x & 63;
    size_t row = (size_t)blockIdx.x*4 + wv;
    float tv = t[row];
    float r1[NT_], te[NT_];
    #pragma unroll
    for (int k = 0; k < NT_; k++) r1[k] = fmaxf(tv*Wt1[k] + bt1[k], 0.f);
    #pragma unroll
    for (int j = 0; j < NT_; j++) {
        float a = bt2[j];
        #pragma unroll
        for (int k = 0; k < NT_; k++) a = fmaf(r1[k], Wt2[k*NT_+j], a);
        te[j] = a;
    }
    if (lane < NT_) t_enc[row*NT_ + lane] = te[lane];
    float x0 = x[row*2+0], x1 = x[row*2+1];
    int c0 = lane*8;
    float af[8], ab[8];
    #pragma unroll
    for (int j = 0; j < 8; j++) {
        int c = c0 + j;
        af[j] = fmaf(x0, Wpf[c], fmaf(x1, Wpf[H_+c], bpf[c]));
        ab[j] = fmaf(x0, Wpb[c], fmaf(x1, Wpb[H_+c], bpb[c]));
    }
    #pragma unroll
    for (int k = 0; k < NT_; k++) {
        #pragma unroll
        for (int j = 0; j < 8; j++) {
            af[j] = fmaf(te[k], Wpf[(2+k)*H_+c0+j], af[j]);
            ab[j] = fmaf(te[k], Wpb[(2+k)*H_+c0+j], ab[j]);
        }
    }
    unsigned short of[8], ob[8];
    #pragma unroll
    for (int j = 0; j < 8; j++) { of[j] = f2b(af[j]); ob[j] = f2b(ab[j]); }
    *(uint4*)&inp_f[row*H_ + c0] = *(const uint4*)of;
    *(uint4*)&inp_b[row*H_ + c0] = *(const uint4*)ob;
}

// ---------------------------------------------------------------------------
// K3g (both dirs): AT{F,B}[row][0..1023] = inp{f,b} @ [Wz|Wh].
// m97-style staging: single-buffered linear LDS tiles (8KB each), per wave
// 2xA + 2xB global_load_lds(16B/lane) per K-step, __syncthreads drains.
// No staging VGPRs -> low VGPR + 16KB LDS -> high co-residency (TLP hides
// latency, m114). Frag reads linear stride (aliasing ok per m97/m98).
// XCD remap; scalar epilogue stores.
// ---------------------------------------------------------------------------
__global__ __launch_bounds__(256) void k3g(
    const unsigned short* __restrict__ inpF,
    const unsigned short* __restrict__ inpB,
    const unsigned short* __restrict__ WTf,   // [1024][512] (Wz rows, Wh rows)
    const unsigned short* __restrict__ WTb,
    unsigned short* __restrict__ ATF,
    unsigned short* __restrict__ ATB,
    int nwg, int halfTiles)
{
    __shared__ __align__(16) unsigned short asL[128*32];   // 8 KB
    __shared__ __align__(16) unsigned short bsL[128*32];   // 8 KB
    int tid = threadIdx.x;
    int lane = tid & 63, w = tid >> 6;
    int wm = w >> 1, wn = w & 1;
    int kg = lane >> 4, lr = lane & 15;

    int bid = blockIdx.x;
    int cpx = nwg >> 3;
    int tile = (bid & 7) * cpx + (bid >> 3);
    int dir  = tile >= halfTiles;
    int lt   = dir ? (tile - halfTiles) : tile;
    int row0 = (lt >> 3) * 128;
    int n0   = (lt & 7) * 128;
    const unsigned short* inp = dir ? inpB : inpF;
    const unsigned short* WT  = dir ? WTb : WTf;
    unsigned short* zt_out    = dir ? ATB : ATF;

    f32x4 acc[4][4];
    #pragma unroll
    for (int m = 0; m < 4; m++)
        #pragma unroll
        for (int n = 0; n < 4; n++) acc[m][n] = (f32x4){0.f,0.f,0.f,0.f};

    // staging geometry: slot u (16B) -> row u>>2, quarter u&3.
    // wave w covers slots [w*128, w*128+128) via 2 instrs of 64 lanes.
    int u0 = w*128 + lane;
    int u1 = u0 + 64;
    const unsigned short* aS0 = &inp[(size_t)(row0 + (u0>>2))*H_ + (u0&3)*8];
    const unsigned short* aS1 = &inp[(size_t)(row0 + (u1>>2))*H_ + (u1&3)*8];
    const unsigned short* bS0 = &WT [(size_t)(n0   + (u0>>2))*H_ + (u0&3)*8];
    const unsigned short* bS1 = &WT [(size_t)(n0   + (u1>>2))*H_ + (u1&3)*8];
    unsigned short* aL0 = &asL[(w*128)*8];          // wave-uniform bases
    unsigned short* aL1 = &asL[(w*128 + 64)*8];
    unsigned short* bL0 = &bsL[(w*128)*8];
    unsigned short* bL1 = &bsL[(w*128 + 64)*8];

    for (int k0 = 0; k0 < H_; k0 += 32) {
        __syncthreads();                 // all waves done reading previous tile
        gld16(aL0, aS0 + k0);
        gld16(aL1, aS1 + k0);
        gld16(bL0, bS0 + k0);
        gld16(bL1, bS1 + k0);
        __syncthreads();                 // drains vmcnt(0) -> LDS ready
        bf16x8 af[4], bf[4];
        #pragma unroll
        for (int m = 0; m < 4; m++)
            af[m] = *(const bf16x8*)&asL[(wm*64 + m*16 + lr)*32 + kg*8];
        #pragma unroll
        for (int n = 0; n < 4; n++)
            bf[n] = *(const bf16x8*)&bsL[(wn*64 + n*16 + lr)*32 + kg*8];
        #pragma unroll
        for (int m = 0; m < 4; m++)
            #pragma unroll
            for (int n = 0; n < 4; n++)
                acc[m][n] = __builtin_amdgcn_mfma_f32_16x16x32_bf16(af[m], bf[n], acc[m][n], 0, 0, 0);
    }

    #pragma unroll
    for (int m = 0; m < 4; m++)
        #pragma unroll
        for (int n = 0; n < 4; n++) {
            int colg = n0 + wn*64 + n*16 + lr;
            #pragma unroll
            for (int r = 0; r < 4; r++) {
                int rowg = row0 + wm*64 + m*16 + kg*4 + r;
                zt_out[(size_t)rowg*NWS_ + colg] = f2b(acc[m][n][r]);
            }
        }
}

// ---------------------------------------------------------------------------
// K4a: bias + activations + chunked scan pass A, in place on AT rows.
// ---------------------------------------------------------------------------
__global__ __launch_bounds__(256) void k4a(
    unsigned short* __restrict__ ATF, unsigned short* __restrict__ ATB,
    const float* __restrict__ bzf, const float* __restrict__ bhf,
    const float* __restrict__ bzb, const float* __restrict__ bhb,
    float* __restrict__ Scar, float* __restrict__ Pcar, int nb)
{
    int g = blockIdx.x*256 + threadIdx.x;
    int col   = g & (H_-1);
    int chunk = (g >> 9) & (CH_-1);
    int rest  = g >> 13;
    int bb    = rest % nb;
    int dir   = rest / nb;
    unsigned short* AT = dir ? ATB : ATF;
    float bzv = (dir ? bzb : bzf)[col];
    float bhv = (dir ? bhb : bhf)[col];
    size_t base = (size_t)bb * L_ * NWS_ + col;
    float h = 0.f, pp = 1.f;
    if (dir == 0) {
        int lo = chunk * CL_;
        for (int p = 0; p < CL_; p += 8) {
            unsigned short zv[8], hv[8];
            #pragma unroll
            for (int j = 0; j < 8; j++) {
                size_t idx = base + (size_t)(lo+p+j)*NWS_;
                zv[j] = AT[idx]; hv[j] = AT[idx + H_];
            }
            #pragma unroll
            for (int j = 0; j < 8; j++) {
                size_t idx = base + (size_t)(lo+p+j)*NWS_;
                float zg = sigmoid_f(b2f(zv[j]) + bzv);
                float a  = 1.f - zg;
                float bg = zg * tanh_f(b2f(hv[j]) + bhv);
                AT[idx]      = f2b(h);
                AT[idx + H_] = f2b(pp);
                h = fmaf(a, h, bg);
                pp *= a;
            }
        }
    } else {
        int hi = chunk * CL_ + CL_ - 1;
        for (int p = 0; p < CL_; p += 8) {
            unsigned short zv[8], hv[8];
            #pragma unroll
            for (int j = 0; j < 8; j++) {
                size_t idx = base + (size_t)(hi-p-j)*NWS_;
                zv[j] = AT[idx]; hv[j] = AT[idx + H_];
            }
            #pragma unroll
            for (int j = 0; j < 8; j++) {
                size_t idx = base + (size_t)(hi-p-j)*NWS_;
                float zg = sigmoid_f(b2f(zv[j]) + bzv);
                float a  = 1.f - zg;
                float bg = zg * tanh_f(b2f(hv[j]) + bhv);
                AT[idx]      = f2b(h);
                AT[idx + H_] = f2b(pp);
                h = fmaf(a, h, bg);
                pp *= a;
            }
        }
    }
    int ci = ((dir*nb + bb)*CH_ + chunk)*H_ + col;
    Scar[ci] = h; Pcar[ci] = pp;
}

// K4b: chain carries across chunks.
__global__ __launch_bounds__(256) void k4b(
    const float* __restrict__ Scar, const float* __restrict__ Pcar,
    float* __restrict__ Hstart, int nb)
{
    int g = blockIdx.x*256 + threadIdx.x;
    int col  = g & (H_-1);
    int rest = g >> 9;
    int bb   = rest % nb;
    int dir  = rest / nb;
    int baseci = (dir*nb + bb)*CH_;
    float h = 0.f;
    if (dir == 0) {
        for (int c = 0; c < CH_; c++) {
            int ci = (baseci + c)*H_ + col;
            Hstart[ci] = h;
            h = Scar[ci] + Pcar[ci]*h;
        }
    } else {
        for (int c = CH_-1; c >= 0; c--) {
            int ci = (baseci + c)*H_ + col;
            Hstart[ci] = h;
            h = Scar[ci] + Pcar[ci]*h;
        }
    }
}

// ---------------------------------------------------------------------------
// K5 fused: LN (rolling-1 prefetch) -> XOR-swizzled LDS A, barrier-free head
// GEMM (3-deep B register pipeline), gelu*Wg2 + shfl row-reduce.
// __launch_bounds__(256,2): keep pipelines live in registers (round-15 win).
// ---------------------------------------------------------------------------
__global__ __launch_bounds__(256, 2) void k5_fused(
    const unsigned short* __restrict__ ATF, const unsigned short* __restrict__ ATB,
    const float* __restrict__ Hstart,
    const float* __restrict__ tenc,
    const float* __restrict__ ln_g, const float* __restrict__ ln_b,
    const float* __restrict__ tsp,
    const uint4* __restrict__ P,              // [33*1024] packed Wg1 fragments
    const float* __restrict__ bg1, const float* __restrict__ Wg2,
    const float* __restrict__ bg2,
    float* __restrict__ out, int nb)
{
    __shared__ __align__(16) unsigned short A[RB5_*ASTR_];   // 68 KB
    __shared__ float red[4][RB5_];
    int tid = threadIdx.x, lane = tid & 63, wv = tid >> 6;
    int kg = lane >> 4, lr = lane & 15;
    int row0 = blockIdx.x * RB5_;
    float ts = tsp[0];

    int bb    = row0 >> 11;          // / L_
    int chunk = (row0 & (L_-1)) >> 7;
    int cif = (bb*CH_ + chunk)*H_;
    int cib = ((nb + bb)*CH_ + chunk)*H_;
    int c0 = lane*8;
    float4 hfa = *(const float4*)&Hstart[cif + c0];
    float4 hfb = *(const float4*)&Hstart[cif + c0 + 4];
    float4 hba = *(const float4*)&Hstart[cib + c0];
    float4 hbb = *(const float4*)&Hstart[cib + c0 + 4];
    float h0f[8] = {hfa.x,hfa.y,hfa.z,hfa.w,hfb.x,hfb.y,hfb.z,hfb.w};
    float h0b[8] = {hba.x,hba.y,hba.z,hba.w,hbb.x,hbb.y,hbb.z,hbb.w};

    float gf[8], bf_[8], gb_[8], bb_[8];
    #pragma unroll
    for (int j = 0; j < 8; j++) {
        gf[j]  = ln_g[c0+j];     bf_[j] = ln_b[c0+j];
        gb_[j] = ln_g[H_+c0+j];  bb_[j] = ln_b[H_+c0+j];
    }
    float gt = 0.f, bt = 0.f;
    if (lane < NT_) { gt = ln_g[2*H_+lane]; bt = ln_b[2*H_+lane]; }

    // ---- LN phase with rolling-1 row prefetch ----
    size_t rowBase = (size_t)(row0 + wv*8) * NWS_;
    uint4 cSF = *(const uint4*)&ATF[rowBase + c0];
    uint4 cPF = *(const uint4*)&ATF[rowBase + H_ + c0];
    uint4 cSB = *(const uint4*)&ATB[rowBase + c0];
    uint4 cPB = *(const uint4*)&ATB[rowBase + H_ + c0];

    #pragma unroll
    for (int i = 0; i < 8; i++) {
        int r = wv*8 + i;
        size_t row = (size_t)row0 + r;
        uint4 SF = cSF, PF = cPF, SB = cSB, PB = cPB;
        if (i < 7) {
            size_t rb2 = rowBase + (size_t)(i+1)*NWS_;
            cSF = *(const uint4*)&ATF[rb2 + c0];
            cPF = *(const uint4*)&ATF[rb2 + H_ + c0];
            cSB = *(const uint4*)&ATB[rb2 + c0];
            cPB = *(const uint4*)&ATB[rb2 + H_ + c0];
        }
        const unsigned short* sf = (const unsigned short*)&SF;
        const unsigned short* pf = (const unsigned short*)&PF;
        const unsigned short* sb = (const unsigned short*)&SB;
        const unsigned short* pb = (const unsigned short*)&PB;
        float fv[8], bv[8];
        float S = 0.f, Q = 0.f;
        #pragma unroll
        for (int j = 0; j < 8; j++) {
            fv[j] = fmaf(b2f(pf[j]), h0f[j], b2f(sf[j]));
            S += fv[j]; Q += fv[j]*fv[j];
            bv[j] = fmaf(b2f(pb[j]), h0b[j], b2f(sb[j]));
            S += bv[j]; Q += bv[j]*bv[j];
        }
        float tv = 0.f;
        if (lane < NT_) { tv = tenc[row*NT_ + lane]; S += tv; Q += tv*tv; }
        #pragma unroll
        for (int off = 32; off > 0; off >>= 1) {
            S += __shfl_xor(S, off, 64);
            Q += __shfl_xor(Q, off, 64);
        }
        float mu = S * (1.f/1032.f);
        float rs = rsqrtf(Q * (1.f/1032.f) - mu*mu + 1e-5f);
        int key = r & 7;
        unsigned short o[8];
        #pragma unroll
        for (int j = 0; j < 8; j++) o[j] = f2b((fv[j]-mu)*rs*gf[j] + bf_[j]);
        *(uint4*)&A[r*ASTR_ + ((lane ^ key)*8)] = *(const uint4*)o;
        #pragma unroll
        for (int j = 0; j < 8; j++) o[j] = f2b((bv[j]-mu)*rs*gb_[j] + bb_[j]);
        *(uint4*)&A[r*ASTR_ + (((64+lane) ^ key)*8)] = *(const uint4*)o;
        if (lane < NT_) {
            A[r*ASTR_ + ((128 ^ key)*8) + lane] =
                f2b(((tv-mu)*rs*gt + bt) * ts);
        } else {
            int cc = 128 + (lane >> 3);
            A[r*ASTR_ + ((cc ^ key)*8) + (lane & 7)] = 0;
        }
    }
    __syncthreads();

    // ---- GEMM phase (no barriers, 3-deep B pipeline) ----
    f32x4 acc[2][4];
    #pragma unroll
    for (int m = 0; m < 2; m++)
        #pragma unroll
        for (int n = 0; n < 4; n++) acc[m][n] = (f32x4){0.f,0.f,0.f,0.f};

    const uint4* Pw = P + wv*256 + lr*4 + kg;
    int keyA = lr & 7;

#define LOADB(v0,v1,v2,v3,KB) do { \
        const uint4* q_ = Pw + (KB)*1024; \
        v0 = *(const bf16x8*)&q_[0]; \
        v1 = *(const bf16x8*)&q_[64]; \
        v2 = *(const bf16x8*)&q_[128]; \
        v3 = *(const bf16x8*)&q_[192]; \
    } while(0)
#define LDSA0(KB) (*(const bf16x8*)&A[lr*ASTR_      + ((((KB)*4+kg) ^ keyA)*8)])
#define LDSA1(KB) (*(const bf16x8*)&A[(16+lr)*ASTR_ + ((((KB)*4+kg) ^ keyA)*8)])
#define MFMA8(v0,v1,v2,v3,a0_,a1_) do { \
        acc[0][0] = __builtin_amdgcn_mfma_f32_16x16x32_bf16(a0_, v0, acc[0][0],0,0,0); \
        acc[0][1] = __builtin_amdgcn_mfma_f32_16x16x32_bf16(a0_, v1, acc[0][1],0,0,0); \
        acc[0][2] = __builtin_amdgcn_mfma_f32_16x16x32_bf16(a0_, v2, acc[0][2],0,0,0); \
        acc[0][3] = __builtin_amdgcn_mfma_f32_16x16x32_bf16(a0_, v3, acc[0][3],0,0,0); \
        acc[1][0] = __builtin_amdgcn_mfma_f32_16x16x32_bf16(a1_, v0, acc[1][0],0,0,0); \
        acc[1][1] = __builtin_amdgcn_mfma_f32_16x16x32_bf16(a1_, v1, acc[1][1],0,0,0); \
        acc[1][2] = __builtin_amdgcn_mfma_f32_16x16x32_bf16(a1_, v2, acc[1][2],0,0,0); \
        acc[1][3] = __builtin_amdgcn_mfma_f32_16x16x32_bf16(a1_, v3, acc[1][3],0,0,0); \
    } while(0)

    bf16x8 a0,a1,a2,a3, d0,d1,d2,d3, e0,e1,e2,e3;
    LOADB(a0,a1,a2,a3, 0);
    LOADB(d0,d1,d2,d3, 1);
    LOADB(e0,e1,e2,e3, 2);
    for (int kb = 0; kb < 30; kb += 3) {
        bf16x8 af0, af1;
        af0 = LDSA0(kb);   af1 = LDSA1(kb);
        MFMA8(a0,a1,a2,a3, af0, af1);
        LOADB(a0,a1,a2,a3, kb+3);
        af0 = LDSA0(kb+1); af1 = LDSA1(kb+1);
        MFMA8(d0,d1,d2,d3, af0, af1);
        LOADB(d0,d1,d2,d3, kb+4);
        af0 = LDSA0(kb+2); af1 = LDSA1(kb+2);
        MFMA8(e0,e1,e2,e3, af0, af1);
        LOADB(e0,e1,e2,e3, kb+5);
    }
    {
        bf16x8 af0, af1;
        af0 = LDSA0(30); af1 = LDSA1(30);
        MFMA8(a0,a1,a2,a3, af0, af1);
        af0 = LDSA0(31); af1 = LDSA1(31);
        MFMA8(d0,d1,d2,d3, af0, af1);
        af0 = LDSA0(32); af1 = LDSA1(32);
        MFMA8(e0,e1,e2,e3, af0, af1);
    }
#undef LOADB
#undef LDSA0
#undef LDSA1
#undef MFMA8

    // ---- epilogue: gelu + *Wg2, reduce over this wave's 64 cols ----
    float rsum[2][4] = {{0.f,0.f,0.f,0.f},{0.f,0.f,0.f,0.f}};
    #pragma unroll
    for (int n = 0; n < 4; n++) {
        int colg = wv*64 + n*16 + lr;
        float bgv = bg1[colg], w2v = Wg2[colg];
        #pragma unroll
        for (int m = 0; m < 2; m++)
            #pragma unroll
            for (int r = 0; r < 4; r++) {
                float gv = gelu_f(acc[m][n][r] + bgv);
                rsum[m][r] = fmaf(gv, w2v, rsum[m][r]);
            }
    }
    #pragma unroll
    for (int off = 1; off < 16; off <<= 1)
        #pragma unroll
        for (int m = 0; m < 2; m++)
            #pragma unroll
            for (int r = 0; r < 4; r++)
                rsum[m][r] += __shfl_xor(rsum[m][r], off, 64);
    if (lr == 0) {
        #pragma unroll
        for (int m = 0; m < 2; m++)
            #pragma unroll
            for (int r = 0; r < 4; r++)
                red[wv][m*16 + kg*4 + r] = rsum[m][r];
    }
    __syncthreads();
    if (tid < RB5_)
        out[row0 + tid] = red[0][tid] + red[1][tid] + red[2][tid] + red[3][tid] + bg2[0];
}

// ---------------------------------------------------------------------------
extern "C" void kernel_launch(void* const* d_in, const int* in_sizes, int n_in,
                              void* d_out, int out_size, void* d_ws, size_t ws_size,
                              hipStream_t stream)
{
    const float* x    = (const float*)d_in[0];
    const float* t    = (const float*)d_in[1];
    const float* Wt1  = (const float*)d_in[2];
    const float* bt1  = (const float*)d_in[3];
    const float* Wt2  = (const float*)d_in[4];
    const float* bt2  = (const float*)d_in[5];
    const float* Wpf  = (const float*)d_in[6];
    const float* bpf  = (const float*)d_in[7];
    const float* Wpb  = (const float*)d_in[8];
    const float* bpb  = (const float*)d_in[9];
    const float* Wzf  = (const float*)d_in[10];
    const float* bzf  = (const float*)d_in[11];
    const float* Whf  = (const float*)d_in[12];
    const float* bhf  = (const float*)d_in[13];
    const float* Wzb  = (const float*)d_in[14];
    const float* bzb  = (const float*)d_in[15];
    const float* Whb  = (const float*)d_in[16];
    const float* bhb  = (const float*)d_in[17];
    const float* ln_g = (const float*)d_in[18];
    const float* ln_b = (const float*)d_in[19];
    const float* tsc  = (const float*)d_in[20];
    const float* Wg1  = (const float*)d_in[21];
    const float* bg1  = (const float*)d_in[22];
    const float* Wg2  = (const float*)d_in[23];
    const float* bg2  = (const float*)d_in[24];
    float* out = (float*)d_out;

    char* p = (char*)d_ws;
    auto carve = [&](size_t bytes) -> char* {
        char* q = p; p += (bytes + 255) & ~(size_t)255; return q;
    };

    unsigned short* WTf = (unsigned short*)carve((size_t)2*H_*H_*2);
    unsigned short* WTb = (unsigned short*)carve((size_t)2*H_*H_*2);
    uint4*          Pg  = (uint4*)carve((size_t)33*1024*16);

    const size_t perBatch = (size_t)L_*H_*2*2          // inpF + inpB
                          + (size_t)L_*NWS_*2*2        // ATF + ATB
                          + (size_t)L_*NT_*4           // tenc
                          + (size_t)CH_*H_*4*3*2;      // carries
    size_t fixedUsed = (size_t)(p - (char*)d_ws) + 64*1024;
    int NB = B_;
    while (NB > 1 && fixedUsed + (size_t)NB*perBatch > ws_size) NB >>= 1;

    unsigned short* inpF = (unsigned short*)carve((size_t)NB*L_*H_*2);
    unsigned short* inpB = (unsigned short*)carve((size_t)NB*L_*H_*2);
    unsigned short* ATF = (unsigned short*)carve((size_t)NB*L_*NWS_*2);
    unsigned short* ATB = (unsigned short*)carve((size_t)NB*L_*NWS_*2);
    float* tenc   = (float*)carve((size_t)NB*L_*NT_*4);
    float* Scar   = (float*)carve((size_t)2*NB*CH_*H_*4);
    float* Pcar   = (float*)carve((size_t)2*NB*CH_*H_*4);
    float* Hstart = (float*)carve((size_t)2*NB*CH_*H_*4);

    {
        dim3 g(H_/32, H_/32);
        kT<<<g, 256, 0, stream>>>(Wzf, WTf,         H_, H_, H_);
        kT<<<g, 256, 0, stream>>>(Whf, WTf + H_*H_, H_, H_, H_);
        kT<<<g, 256, 0, stream>>>(Wzb, WTb,         H_, H_, H_);
        kT<<<g, 256, 0, stream>>>(Whb, WTb + H_*H_, H_, H_, H_);
        kP<<<132, 256, 0, stream>>>(Wg1, Pg);
    }

    for (int b0 = 0; b0 < B_; b0 += NB) {
        int rows = NB * L_;
        int halfTiles = (rows/128) * 8;
        int nwg3 = 2 * halfTiles;

        k1_tenc_inp<<<rows/4, 256, 0, stream>>>(
            x + (size_t)b0*L_*2, t + (size_t)b0*L_,
            Wt1, bt1, Wt2, bt2, Wpf, bpf, Wpb, bpb,
            tenc, inpF, inpB);

        k3g<<<nwg3, 256, 0, stream>>>(inpF, inpB, WTf, WTb, ATF, ATB,
                                      nwg3, halfTiles);

        int scanThreads = 2*NB*H_*CH_;
        k4a<<<scanThreads/256, 256, 0, stream>>>(ATF, ATB, bzf, bhf, bzb, bhb,
                                                 Scar, Pcar, NB);
        k4b<<<(2*NB*H_)/256, 256, 0, stream>>>(Scar, Pcar, Hstart, NB);

        k5_fused<<<rows/RB5_, 256, 0, stream>>>(
            ATF, ATB, Hstart, tenc, ln_g, ln_b, tsc,
            Pg, bg1, Wg2, bg2, out + (size_t)b0*L_, NB);
    }
}